// Round 1
// baseline (807.203 us; speedup 1.0000x reference)
//
#include <hip/hip_runtime.h>
#include <hip/hip_bf16.h>

#define NEG_SLOPE 0.2f
#define EPS_BN 1e-5f
#define EPS_SM 1e-16f

__device__ __forceinline__ float leaky(float x) { return x > 0.f ? x : NEG_SLOPE * x; }

// ---------------- edge dtype detection (int32 vs int64 layout) ----------------
__global__ void k_detect(const int* __restrict__ ei, int* __restrict__ cnt, int e) {
    int i = threadIdx.x + blockIdx.x * blockDim.x;
    if (i < 1024 && 2 * i + 1 < 2 * e) {
        if (ei[2 * i + 1] != 0) atomicAdd(cnt, 1);
    }
}

// ---------------- CSR build ----------------
__global__ void k_hist(const int* __restrict__ ei, const int* __restrict__ cnt,
                       int* __restrict__ deg, int e) {
    int g = threadIdx.x + blockIdx.x * blockDim.x;
    if (g >= e) return;
    bool is64 = (*cnt) < 512;
    int d = is64 ? ei[2 * (e + g)] : ei[e + g];
    atomicAdd(&deg[d], 1);
}

__global__ __launch_bounds__(1024) void k_scan1(const int* __restrict__ deg,
                                                int* __restrict__ excl,
                                                int* __restrict__ bsum, int n) {
    __shared__ int sm[1024];
    int tid = threadIdx.x;
    int g = blockIdx.x * 1024 + tid;
    int v = (g < n) ? deg[g] : 0;
    sm[tid] = v;
    __syncthreads();
    for (int off = 1; off < 1024; off <<= 1) {
        int t = (tid >= off) ? sm[tid - off] : 0;
        __syncthreads();
        sm[tid] += t;
        __syncthreads();
    }
    if (g < n) excl[g] = sm[tid] - v;
    if (tid == 1023) bsum[blockIdx.x] = sm[1023];
}

__global__ void k_scan2(int* bsum, int nb) {
    if (threadIdx.x == 0 && blockIdx.x == 0) {
        int acc = 0;
        for (int i = 0; i < nb; ++i) { int v = bsum[i]; bsum[i] = acc; acc += v; }
    }
}

__global__ void k_scan3(const int* __restrict__ excl, const int* __restrict__ bsum,
                        int* __restrict__ rowptr, int n, int e) {
    int g = threadIdx.x + blockIdx.x * blockDim.x;
    if (g < n) rowptr[g] = excl[g] + bsum[g >> 10];
    if (g == 0) rowptr[n] = e;
}

__global__ void k_scatter(const int* __restrict__ ei, const int* __restrict__ cnt,
                          const int* __restrict__ rowptr, int* __restrict__ fill,
                          int* __restrict__ col, int e) {
    int g = threadIdx.x + blockIdx.x * blockDim.x;
    if (g >= e) return;
    bool is64 = (*cnt) < 512;
    int s = is64 ? ei[2 * g] : ei[g];
    int d = is64 ? ei[2 * (e + g)] : ei[e + g];
    int pos = rowptr[d] + atomicAdd(&fill[d], 1);
    col[pos] = s;
}

// ---------------- fp32 GEMM: C[n,M] = A[n,K] @ B[K,M] (+bias) ----------------
__global__ __launch_bounds__(256) void k_gemm(const float* __restrict__ A,
                                              const float* __restrict__ B,
                                              float* __restrict__ C,
                                              const float* __restrict__ bias,
                                              int n, int K, int M) {
    __shared__ float As[16][68];
    __shared__ float Bs[16][64];
    const int tx = threadIdx.x & 15, ty = threadIdx.x >> 4;
    const int row0 = blockIdx.y * 64, col0 = blockIdx.x * 64;
    float acc[4][4] = {};
    for (int kt = 0; kt < K; kt += 16) {
        {
            int r = threadIdx.x >> 2, kk = (threadIdx.x & 3) * 4;
            int grow = row0 + r;
            float4 v = make_float4(0.f, 0.f, 0.f, 0.f);
            if (grow < n) v = *reinterpret_cast<const float4*>(A + (size_t)grow * K + kt + kk);
            As[kk + 0][r] = v.x; As[kk + 1][r] = v.y; As[kk + 2][r] = v.z; As[kk + 3][r] = v.w;
        }
        {
            int kr = threadIdx.x >> 4, m4 = (threadIdx.x & 15) * 4;
            float4 v = *reinterpret_cast<const float4*>(B + (size_t)(kt + kr) * M + col0 + m4);
            *reinterpret_cast<float4*>(&Bs[kr][m4]) = v;
        }
        __syncthreads();
#pragma unroll
        for (int k = 0; k < 16; ++k) {
            float4 a = *reinterpret_cast<const float4*>(&As[k][ty * 4]);
            float4 b = *reinterpret_cast<const float4*>(&Bs[k][tx * 4]);
            float av[4] = {a.x, a.y, a.z, a.w};
            float bv[4] = {b.x, b.y, b.z, b.w};
#pragma unroll
            for (int i = 0; i < 4; ++i)
#pragma unroll
                for (int j = 0; j < 4; ++j) acc[i][j] += av[i] * bv[j];
        }
        __syncthreads();
    }
#pragma unroll
    for (int i = 0; i < 4; ++i) {
        int r = row0 + ty * 4 + i;
        if (r < n) {
#pragma unroll
            for (int j = 0; j < 4; ++j) {
                int c = col0 + tx * 4 + j;
                float v = acc[i][j];
                if (bias) v += bias[c];
                C[(size_t)r * M + c] = v;
            }
        }
    }
}

// ---------------- attention coefficients: a_src/a_dst [n,2] ----------------
template <int C>
__global__ __launch_bounds__(256) void k_attn(const float* __restrict__ xh,
                                              const float* __restrict__ att_s,
                                              const float* __restrict__ att_d,
                                              float* __restrict__ asrc,
                                              float* __restrict__ adst, int n) {
    constexpr int VEC = (2 * C) / 64;
    int wave = (blockIdx.x * blockDim.x + threadIdx.x) >> 6;
    int lane = threadIdx.x & 63;
    if (wave >= n) return;
    const float* row = xh + (size_t)wave * (2 * C) + lane * VEC;
    float ps = 0.f, pd = 0.f;
#pragma unroll
    for (int q = 0; q < VEC; ++q) {
        float v = row[q];
        ps += v * att_s[lane * VEC + q];
        pd += v * att_d[lane * VEC + q];
    }
#pragma unroll
    for (int off = 1; off <= 16; off <<= 1) {
        ps += __shfl_xor(ps, off);
        pd += __shfl_xor(pd, off);
    }
    if ((lane & 31) == 0) {
        int h = lane >> 5;
        asrc[2 * wave + h] = ps;
        adst[2 * wave + h] = pd;
    }
}

// ---------------- GAT aggregation (segment softmax + gather) ----------------
template <int C>
__global__ __launch_bounds__(256) void k_agg(const float* __restrict__ xh,
                                             const float* __restrict__ asrc,
                                             const float* __restrict__ adst,
                                             const int* __restrict__ rowptr,
                                             const int* __restrict__ col,
                                             const float* __restrict__ bias,
                                             float* __restrict__ out, int n) {
    constexpr int VEC = (2 * C) / 64;
    int wave = (blockIdx.x * blockDim.x + threadIdx.x) >> 6;
    int lane = threadIdx.x & 63;
    if (wave >= n) return;
    const int i = wave;
    const int head = lane >> 5;  // 0 or 1 for both C=128(VEC4) and C=64(VEC2)
    const int beg = rowptr[i];
    const int deg = rowptr[i + 1] - beg;
    const float ad0 = adst[2 * i], ad1 = adst[2 * i + 1];
    const float as0 = asrc[2 * i], as1 = asrc[2 * i + 1];
    const float es0 = leaky(as0 + ad0), es1 = leaky(as1 + ad1);
    float m0 = es0, m1 = es1;
    for (int j = lane; j < deg; j += 64) {
        int s = col[beg + j];
        m0 = fmaxf(m0, leaky(asrc[2 * s] + ad0));
        m1 = fmaxf(m1, leaky(asrc[2 * s + 1] + ad1));
    }
#pragma unroll
    for (int off = 1; off <= 32; off <<= 1) {
        m0 = fmaxf(m0, __shfl_xor(m0, off));
        m1 = fmaxf(m1, __shfl_xor(m1, off));
    }
    float acc[VEC] = {};
    float d0 = 0.f, d1 = 0.f;
    for (int base = 0; base < deg; base += 64) {
        int cnt = min(64, deg - base);
        float ex0 = 0.f, ex1 = 0.f;
        int s = 0;
        if (lane < cnt) {
            s = col[beg + base + lane];
            ex0 = expf(leaky(asrc[2 * s] + ad0) - m0);
            ex1 = expf(leaky(asrc[2 * s + 1] + ad1) - m1);
        }
        d0 += ex0; d1 += ex1;
        for (int j = 0; j < cnt; ++j) {
            float w0 = __shfl(ex0, j);
            float w1 = __shfl(ex1, j);
            int sj = __shfl(s, j);
            float w = head ? w1 : w0;
            const float* p = xh + (size_t)sj * (2 * C) + lane * VEC;
            float r[VEC];
            if constexpr (VEC == 4) {
                float4 t = *reinterpret_cast<const float4*>(p);
                r[0] = t.x; r[1] = t.y; r[2] = t.z; r[3] = t.w;
            } else {
                float2 t = *reinterpret_cast<const float2*>(p);
                r[0] = t.x; r[1] = t.y;
            }
#pragma unroll
            for (int q = 0; q < VEC; ++q) acc[q] += w * r[q];
        }
    }
#pragma unroll
    for (int off = 1; off <= 32; off <<= 1) {
        d0 += __shfl_xor(d0, off);
        d1 += __shfl_xor(d1, off);
    }
    // self loop
    float exs0 = expf(es0 - m0), exs1 = expf(es1 - m1);
    d0 += exs0; d1 += exs1;
    {
        float w = head ? exs1 : exs0;
        const float* p = xh + (size_t)i * (2 * C) + lane * VEC;
        float r[VEC];
        if constexpr (VEC == 4) {
            float4 t = *reinterpret_cast<const float4*>(p);
            r[0] = t.x; r[1] = t.y; r[2] = t.z; r[3] = t.w;
        } else {
            float2 t = *reinterpret_cast<const float2*>(p);
            r[0] = t.x; r[1] = t.y;
        }
#pragma unroll
        for (int q = 0; q < VEC; ++q) acc[q] += w * r[q];
    }
    float inv = 1.0f / ((head ? d1 : d0) + EPS_SM);
    float* po = out + (size_t)i * (2 * C) + lane * VEC;
    float o[VEC];
#pragma unroll
    for (int q = 0; q < VEC; ++q) o[q] = fmaxf(acc[q] * inv + bias[lane * VEC + q], 0.f);
    if constexpr (VEC == 4) {
        *reinterpret_cast<float4*>(po) = make_float4(o[0], o[1], o[2], o[3]);
    } else {
        *reinterpret_cast<float2*>(po) = make_float2(o[0], o[1]);
    }
}

// ---------------- BatchNorm ----------------
__global__ void k_bn_stats(const float* __restrict__ x, float* __restrict__ sums,
                           float* __restrict__ sqs, int n, int f) {
    int c = threadIdx.x;  // blockDim.x == f
    float s = 0.f, q = 0.f;
    for (int r = blockIdx.x; r < n; r += gridDim.x) {
        float v = x[(size_t)r * f + c];
        s += v; q += v * v;
    }
    atomicAdd(&sums[c], s);
    atomicAdd(&sqs[c], q);
}

__global__ void k_bn_norm(float* __restrict__ x, const float* __restrict__ sums,
                          const float* __restrict__ sqs, const float* __restrict__ g,
                          const float* __restrict__ b, int n, int f) {
    int idx = threadIdx.x + blockIdx.x * blockDim.x;
    if (idx >= n * f) return;
    int c = idx & (f - 1);  // f power of two (256/128)
    float mean = sums[c] / n;
    float var = sqs[c] / n - mean * mean;
    x[idx] = (x[idx] - mean) * rsqrtf(var + EPS_BN) * g[c] + b[c];
}

// ---------------- launch ----------------
extern "C" void kernel_launch(void* const* d_in, const int* in_sizes, int n_in,
                              void* d_out, int out_size, void* d_ws, size_t ws_size,
                              hipStream_t stream) {
    const float* x   = (const float*)d_in[0];
    const int*   ei  = (const int*)d_in[1];
    const float* W1  = (const float*)d_in[2];
    const float* as1 = (const float*)d_in[3];
    const float* ad1 = (const float*)d_in[4];
    const float* b1  = (const float*)d_in[5];
    const float* g1  = (const float*)d_in[6];
    const float* be1 = (const float*)d_in[7];
    const float* W2  = (const float*)d_in[8];
    const float* as2 = (const float*)d_in[9];
    const float* ad2 = (const float*)d_in[10];
    const float* b2  = (const float*)d_in[11];
    const float* g2  = (const float*)d_in[12];
    const float* be2 = (const float*)d_in[13];
    const float* W3  = (const float*)d_in[14];
    const float* as3 = (const float*)d_in[15];
    const float* ad3 = (const float*)d_in[16];
    const float* b3  = (const float*)d_in[17];
    const float* lw  = (const float*)d_in[18];
    const float* lb  = (const float*)d_in[19];
    float* outp = (float*)d_out;

    const int n = in_sizes[0] / 128;  // 50000
    const int e = in_sizes[1] / 2;    // 800000

    // workspace layout
    char* w = (char*)d_ws;
    size_t off = 0;
    auto alloc = [&](size_t bytes) -> void* {
        void* p = w + off;
        off += (bytes + 255) & ~(size_t)255;
        return p;
    };
    float* bufA   = (float*)alloc((size_t)n * 256 * 4);
    float* bufB   = (float*)alloc((size_t)n * 256 * 4);
    float* asrc   = (float*)alloc((size_t)n * 2 * 4);
    float* adst   = (float*)alloc((size_t)n * 2 * 4);
    float* bnstat = (float*)alloc(512 * 4);  // sums [0..255], sqs [256..511]
    int* deg    = (int*)alloc((size_t)n * 4);
    int* excl   = (int*)alloc((size_t)n * 4);
    int* rowptr = (int*)alloc((size_t)(n + 1) * 4);
    int* fill   = (int*)alloc((size_t)n * 4);
    int* colb   = (int*)alloc((size_t)e * 4);
    int* bsum   = (int*)alloc(64 * 4);
    int* dcnt   = (int*)alloc(64 * 4);

    const int nb1 = (n + 1023) / 1024;

    // edge dtype detect
    hipMemsetAsync(dcnt, 0, 4, stream);
    k_detect<<<4, 256, 0, stream>>>(ei, dcnt, e);

    // CSR
    hipMemsetAsync(deg, 0, (size_t)n * 4, stream);
    k_hist<<<(e + 255) / 256, 256, 0, stream>>>(ei, dcnt, deg, e);
    k_scan1<<<nb1, 1024, 0, stream>>>(deg, excl, bsum, n);
    k_scan2<<<1, 1, 0, stream>>>(bsum, nb1);
    k_scan3<<<(n + 255) / 256, 256, 0, stream>>>(excl, bsum, rowptr, n, e);
    hipMemsetAsync(fill, 0, (size_t)n * 4, stream);
    k_scatter<<<(e + 255) / 256, 256, 0, stream>>>(ei, dcnt, rowptr, fill, colb, e);

    const int nwb = (n + 3) / 4;  // wave-per-node blocks (4 waves/block)

    // ---- layer 1: 128 -> 2x128 ----
    {
        dim3 g(256 / 64, (n + 63) / 64);
        k_gemm<<<g, 256, 0, stream>>>(x, W1, bufA, nullptr, n, 128, 256);
    }
    k_attn<128><<<nwb, 256, 0, stream>>>(bufA, as1, ad1, asrc, adst, n);
    k_agg<128><<<nwb, 256, 0, stream>>>(bufA, asrc, adst, rowptr, colb, b1, bufB, n);
    hipMemsetAsync(bnstat, 0, 512 * 4, stream);
    k_bn_stats<<<256, 256, 0, stream>>>(bufB, bnstat, bnstat + 256, n, 256);
    k_bn_norm<<<((size_t)n * 256 + 255) / 256, 256, 0, stream>>>(bufB, bnstat, bnstat + 256, g1, be1, n, 256);

    // ---- layer 2: 256 -> 2x64 ----
    {
        dim3 g(128 / 64, (n + 63) / 64);
        k_gemm<<<g, 256, 0, stream>>>(bufB, W2, bufA, nullptr, n, 256, 128);
    }
    k_attn<64><<<nwb, 256, 0, stream>>>(bufA, as2, ad2, asrc, adst, n);
    k_agg<64><<<nwb, 256, 0, stream>>>(bufA, asrc, adst, rowptr, colb, b2, bufB, n);
    hipMemsetAsync(bnstat, 0, 512 * 4, stream);
    k_bn_stats<<<256, 128, 0, stream>>>(bufB, bnstat, bnstat + 256, n, 128);
    k_bn_norm<<<((size_t)n * 128 + 255) / 256, 256, 0, stream>>>(bufB, bnstat, bnstat + 256, g2, be2, n, 128);

    // ---- layer 3: 128 -> 2x64 ----
    {
        dim3 g(128 / 64, (n + 63) / 64);
        k_gemm<<<g, 256, 0, stream>>>(bufB, W3, bufA, nullptr, n, 128, 128);
    }
    k_attn<64><<<nwb, 256, 0, stream>>>(bufA, as3, ad3, asrc, adst, n);
    k_agg<64><<<nwb, 256, 0, stream>>>(bufA, asrc, adst, rowptr, colb, b3, bufB, n);

    // ---- final linear: [n,128] @ [128,64] + lb ----
    {
        dim3 g(64 / 64, (n + 63) / 64);
        k_gemm<<<g, 256, 0, stream>>>(bufB, lw, outp, lb, n, 128, 64);
    }
}

// Round 2
// 664.607 us; speedup vs baseline: 1.2146x; 1.2146x over previous
//
#include <hip/hip_runtime.h>
#include <hip/hip_bf16.h>

#define NEG_SLOPE 0.2f
#define EPS_BN 1e-5f
#define EPS_SM 1e-16f

typedef __bf16 bf16x8 __attribute__((ext_vector_type(8)));
typedef __bf16 bf16x4 __attribute__((ext_vector_type(4)));
typedef __bf16 bf16x2 __attribute__((ext_vector_type(2)));
typedef float floatx4 __attribute__((ext_vector_type(4)));

__device__ __forceinline__ float leaky(float x) { return x > 0.f ? x : NEG_SLOPE * x; }

// ---------------- edge dtype detection (int32 vs int64 layout) ----------------
__global__ void k_detect(const int* __restrict__ ei, int* __restrict__ cnt, int e) {
    int i = threadIdx.x + blockIdx.x * blockDim.x;
    if (i < 1024 && 2 * i + 1 < 2 * e) {
        if (ei[2 * i + 1] != 0) atomicAdd(cnt, 1);
    }
}

// ---------------- CSR build ----------------
__global__ void k_hist(const int* __restrict__ ei, const int* __restrict__ cnt,
                       int* __restrict__ deg, int e) {
    int g = threadIdx.x + blockIdx.x * blockDim.x;
    if (g >= e) return;
    bool is64 = (*cnt) < 512;
    int d = is64 ? ei[2 * (e + g)] : ei[e + g];
    atomicAdd(&deg[d], 1);
}

__global__ __launch_bounds__(1024) void k_scan1(const int* __restrict__ deg,
                                                int* __restrict__ excl,
                                                int* __restrict__ bsum, int n) {
    __shared__ int sm[1024];
    int tid = threadIdx.x;
    int g = blockIdx.x * 1024 + tid;
    int v = (g < n) ? deg[g] : 0;
    sm[tid] = v;
    __syncthreads();
    for (int off = 1; off < 1024; off <<= 1) {
        int t = (tid >= off) ? sm[tid - off] : 0;
        __syncthreads();
        sm[tid] += t;
        __syncthreads();
    }
    if (g < n) excl[g] = sm[tid] - v;
    if (tid == 1023) bsum[blockIdx.x] = sm[1023];
}

__global__ void k_scan2(int* bsum, int nb) {
    if (threadIdx.x == 0 && blockIdx.x == 0) {
        int acc = 0;
        for (int i = 0; i < nb; ++i) { int v = bsum[i]; bsum[i] = acc; acc += v; }
    }
}

__global__ void k_scan3(const int* __restrict__ excl, const int* __restrict__ bsum,
                        int* __restrict__ rowptr, int n, int e) {
    int g = threadIdx.x + blockIdx.x * blockDim.x;
    if (g < n) rowptr[g] = excl[g] + bsum[g >> 10];
    if (g == 0) rowptr[n] = e;
}

__global__ void k_scatter(const int* __restrict__ ei, const int* __restrict__ cnt,
                          const int* __restrict__ rowptr, int* __restrict__ fill,
                          int* __restrict__ col, int e) {
    int g = threadIdx.x + blockIdx.x * blockDim.x;
    if (g >= e) return;
    bool is64 = (*cnt) < 512;
    int s = is64 ? ei[2 * g] : ei[g];
    int d = is64 ? ei[2 * (e + g)] : ei[e + g];
    int pos = rowptr[d] + atomicAdd(&fill[d], 1);
    col[pos] = s;
}

// ---------------- weight convert+transpose: Wb[m][k] = bf16(W[k][m]) ----------------
__global__ void k_wconv(const float* __restrict__ W, __bf16* __restrict__ Wb,
                        int kshift, int M, int total) {
    int idx = threadIdx.x + blockIdx.x * blockDim.x;
    if (idx >= total) return;
    int mm = idx >> kshift;
    int kk = idx & ((1 << kshift) - 1);
    Wb[idx] = (__bf16)W[(size_t)kk * M + mm];
}

// ---------------- bf16 MFMA GEMM: Cb[n,M](bf16) = A[n,K](f32) @ Bt[M,K](bf16)^T ----
template <int K>
__global__ __launch_bounds__(256) void k_gemm_mfma(const float* __restrict__ A,
                                                   const __bf16* __restrict__ Bt,
                                                   __bf16* __restrict__ Cb,
                                                   int n, int M) {
    __shared__ __align__(16) __bf16 As[64][72];
    __shared__ __align__(16) __bf16 Bs[64][72];
    const int row0 = blockIdx.y * 64, col0 = blockIdx.x * 64;
    const int lane = threadIdx.x & 63, w = threadIdx.x >> 6;
    const int m = lane & 15, quad = lane >> 4;
    floatx4 acc[4];
#pragma unroll
    for (int i = 0; i < 4; ++i) acc[i] = (floatx4)0.f;

    const int sr = threadIdx.x >> 2;         // 0..63
    const int skq = (threadIdx.x & 3) * 16;  // 0,16,32,48

    for (int kc = 0; kc < K; kc += 64) {
        // stage A (fp32 -> bf16)
        {
            int grow = row0 + sr;
            if (grow < n) {
                const float* p = A + (size_t)grow * K + kc + skq;
#pragma unroll
                for (int q = 0; q < 4; ++q) {
                    float4 v = *reinterpret_cast<const float4*>(p + q * 4);
                    bf16x4 c = {(__bf16)v.x, (__bf16)v.y, (__bf16)v.z, (__bf16)v.w};
                    *reinterpret_cast<bf16x4*>(&As[sr][skq + q * 4]) = c;
                }
            } else {
#pragma unroll
                for (int q = 0; q < 4; ++q)
                    *reinterpret_cast<bf16x4*>(&As[sr][skq + q * 4]) = (bf16x4)(__bf16)0.f;
            }
        }
        // stage B (already bf16, [M][K] row-major -> straight copy)
        {
            const __bf16* p = Bt + (size_t)(col0 + sr) * K + kc + skq;
            bf16x8 b0 = *reinterpret_cast<const bf16x8*>(p);
            bf16x8 b1 = *reinterpret_cast<const bf16x8*>(p + 8);
            *reinterpret_cast<bf16x8*>(&Bs[sr][skq]) = b0;
            *reinterpret_cast<bf16x8*>(&Bs[sr][skq + 8]) = b1;
        }
        __syncthreads();
#pragma unroll
        for (int ks = 0; ks < 64; ks += 32) {
            bf16x8 a = *reinterpret_cast<const bf16x8*>(&As[w * 16 + m][ks + quad * 8]);
#pragma unroll
            for (int nt = 0; nt < 4; ++nt) {
                bf16x8 b = *reinterpret_cast<const bf16x8*>(&Bs[nt * 16 + m][ks + quad * 8]);
                acc[nt] = __builtin_amdgcn_mfma_f32_16x16x32_bf16(a, b, acc[nt], 0, 0, 0);
            }
        }
        __syncthreads();
    }
#pragma unroll
    for (int nt = 0; nt < 4; ++nt) {
#pragma unroll
        for (int r = 0; r < 4; ++r) {
            int row = row0 + w * 16 + quad * 4 + r;
            if (row < n) Cb[(size_t)row * M + col0 + nt * 16 + m] = (__bf16)acc[nt][r];
        }
    }
}

// ---------------- fp32 GEMM (final linear): C[n,M] = A[n,K] @ B[K,M] (+bias) -------
__global__ __launch_bounds__(256) void k_gemm(const float* __restrict__ A,
                                              const float* __restrict__ B,
                                              float* __restrict__ C,
                                              const float* __restrict__ bias,
                                              int n, int K, int M) {
    __shared__ float As[16][68];
    __shared__ float Bs[16][64];
    const int tx = threadIdx.x & 15, ty = threadIdx.x >> 4;
    const int row0 = blockIdx.y * 64, col0 = blockIdx.x * 64;
    float acc[4][4] = {};
    for (int kt = 0; kt < K; kt += 16) {
        {
            int r = threadIdx.x >> 2, kk = (threadIdx.x & 3) * 4;
            int grow = row0 + r;
            float4 v = make_float4(0.f, 0.f, 0.f, 0.f);
            if (grow < n) v = *reinterpret_cast<const float4*>(A + (size_t)grow * K + kt + kk);
            As[kk + 0][r] = v.x; As[kk + 1][r] = v.y; As[kk + 2][r] = v.z; As[kk + 3][r] = v.w;
        }
        {
            int kr = threadIdx.x >> 4, m4 = (threadIdx.x & 15) * 4;
            float4 v = *reinterpret_cast<const float4*>(B + (size_t)(kt + kr) * M + col0 + m4);
            *reinterpret_cast<float4*>(&Bs[kr][m4]) = v;
        }
        __syncthreads();
#pragma unroll
        for (int k = 0; k < 16; ++k) {
            float4 a = *reinterpret_cast<const float4*>(&As[k][ty * 4]);
            float4 b = *reinterpret_cast<const float4*>(&Bs[k][tx * 4]);
            float av[4] = {a.x, a.y, a.z, a.w};
            float bv[4] = {b.x, b.y, b.z, b.w};
#pragma unroll
            for (int i = 0; i < 4; ++i)
#pragma unroll
                for (int j = 0; j < 4; ++j) acc[i][j] += av[i] * bv[j];
        }
        __syncthreads();
    }
#pragma unroll
    for (int i = 0; i < 4; ++i) {
        int r = row0 + ty * 4 + i;
        if (r < n) {
#pragma unroll
            for (int j = 0; j < 4; ++j) {
                int c = col0 + tx * 4 + j;
                float v = acc[i][j];
                if (bias) v += bias[c];
                C[(size_t)r * M + c] = v;
            }
        }
    }
}

// ---------------- attention coefficients: a_src/a_dst [n,2] (bf16 xh) -------------
template <int C>
__global__ __launch_bounds__(256) void k_attn(const __bf16* __restrict__ xh,
                                              const float* __restrict__ att_s,
                                              const float* __restrict__ att_d,
                                              float* __restrict__ asrc,
                                              float* __restrict__ adst, int n) {
    constexpr int VEC = (2 * C) / 64;
    int wave = (blockIdx.x * blockDim.x + threadIdx.x) >> 6;
    int lane = threadIdx.x & 63;
    if (wave >= n) return;
    const __bf16* row = xh + (size_t)wave * (2 * C) + lane * VEC;
    float ps = 0.f, pd = 0.f;
#pragma unroll
    for (int q = 0; q < VEC; ++q) {
        float v = (float)row[q];
        ps += v * att_s[lane * VEC + q];
        pd += v * att_d[lane * VEC + q];
    }
#pragma unroll
    for (int off = 1; off <= 16; off <<= 1) {
        ps += __shfl_xor(ps, off);
        pd += __shfl_xor(pd, off);
    }
    if ((lane & 31) == 0) {
        int h = lane >> 5;
        asrc[2 * wave + h] = ps;
        adst[2 * wave + h] = pd;
    }
}

// ---------------- GAT aggregation (segment softmax + bf16 gather) ----------------
template <int C>
__global__ __launch_bounds__(256) void k_agg(const __bf16* __restrict__ xh,
                                             const float* __restrict__ asrc,
                                             const float* __restrict__ adst,
                                             const int* __restrict__ rowptr,
                                             const int* __restrict__ col,
                                             const float* __restrict__ bias,
                                             float* __restrict__ out, int n) {
    constexpr int VEC = (2 * C) / 64;
    int wave = (blockIdx.x * blockDim.x + threadIdx.x) >> 6;
    int lane = threadIdx.x & 63;
    if (wave >= n) return;
    const int i = wave;
    const int head = lane >> 5;  // 0 or 1 for both C=128(VEC4) and C=64(VEC2)
    const int beg = rowptr[i];
    const int deg = rowptr[i + 1] - beg;
    const float ad0 = adst[2 * i], ad1 = adst[2 * i + 1];
    const float as0 = asrc[2 * i], as1 = asrc[2 * i + 1];
    const float es0 = leaky(as0 + ad0), es1 = leaky(as1 + ad1);
    float m0 = es0, m1 = es1;
    for (int j = lane; j < deg; j += 64) {
        int s = col[beg + j];
        m0 = fmaxf(m0, leaky(asrc[2 * s] + ad0));
        m1 = fmaxf(m1, leaky(asrc[2 * s + 1] + ad1));
    }
#pragma unroll
    for (int off = 1; off <= 32; off <<= 1) {
        m0 = fmaxf(m0, __shfl_xor(m0, off));
        m1 = fmaxf(m1, __shfl_xor(m1, off));
    }
    float acc[VEC] = {};
    float d0 = 0.f, d1 = 0.f;
    for (int base = 0; base < deg; base += 64) {
        int cnt = min(64, deg - base);
        float ex0 = 0.f, ex1 = 0.f;
        int s = 0;
        if (lane < cnt) {
            s = col[beg + base + lane];
            ex0 = expf(leaky(asrc[2 * s] + ad0) - m0);
            ex1 = expf(leaky(asrc[2 * s + 1] + ad1) - m1);
        }
        d0 += ex0; d1 += ex1;
        for (int j = 0; j < cnt; ++j) {
            float w0 = __shfl(ex0, j);
            float w1 = __shfl(ex1, j);
            int sj = __shfl(s, j);
            float w = head ? w1 : w0;
            const __bf16* p = xh + (size_t)sj * (2 * C) + lane * VEC;
            float r[VEC];
            if constexpr (VEC == 4) {
                bf16x4 t = *reinterpret_cast<const bf16x4*>(p);
                r[0] = (float)t.x; r[1] = (float)t.y; r[2] = (float)t.z; r[3] = (float)t.w;
            } else {
                bf16x2 t = *reinterpret_cast<const bf16x2*>(p);
                r[0] = (float)t.x; r[1] = (float)t.y;
            }
#pragma unroll
            for (int q = 0; q < VEC; ++q) acc[q] += w * r[q];
        }
    }
#pragma unroll
    for (int off = 1; off <= 32; off <<= 1) {
        d0 += __shfl_xor(d0, off);
        d1 += __shfl_xor(d1, off);
    }
    // self loop
    float exs0 = expf(es0 - m0), exs1 = expf(es1 - m1);
    d0 += exs0; d1 += exs1;
    {
        float w = head ? exs1 : exs0;
        const __bf16* p = xh + (size_t)i * (2 * C) + lane * VEC;
        float r[VEC];
        if constexpr (VEC == 4) {
            bf16x4 t = *reinterpret_cast<const bf16x4*>(p);
            r[0] = (float)t.x; r[1] = (float)t.y; r[2] = (float)t.z; r[3] = (float)t.w;
        } else {
            bf16x2 t = *reinterpret_cast<const bf16x2*>(p);
            r[0] = (float)t.x; r[1] = (float)t.y;
        }
#pragma unroll
        for (int q = 0; q < VEC; ++q) acc[q] += w * r[q];
    }
    float inv = 1.0f / ((head ? d1 : d0) + EPS_SM);
    float* po = out + (size_t)i * (2 * C) + lane * VEC;
    float o[VEC];
#pragma unroll
    for (int q = 0; q < VEC; ++q) o[q] = fmaxf(acc[q] * inv + bias[lane * VEC + q], 0.f);
    if constexpr (VEC == 4) {
        *reinterpret_cast<float4*>(po) = make_float4(o[0], o[1], o[2], o[3]);
    } else {
        *reinterpret_cast<float2*>(po) = make_float2(o[0], o[1]);
    }
}

// ---------------- BatchNorm ----------------
__global__ void k_bn_stats(const float* __restrict__ x, float* __restrict__ sums,
                           float* __restrict__ sqs, int n, int f) {
    int c = threadIdx.x;  // blockDim.x == f
    float s = 0.f, q = 0.f;
    for (int r = blockIdx.x; r < n; r += gridDim.x) {
        float v = x[(size_t)r * f + c];
        s += v; q += v * v;
    }
    atomicAdd(&sums[c], s);
    atomicAdd(&sqs[c], q);
}

__global__ void k_bn_norm(float* __restrict__ x, const float* __restrict__ sums,
                          const float* __restrict__ sqs, const float* __restrict__ g,
                          const float* __restrict__ b, int n, int f) {
    int idx = threadIdx.x + blockIdx.x * blockDim.x;
    if (idx >= n * f) return;
    int c = idx & (f - 1);  // f power of two (256/128)
    float mean = sums[c] / n;
    float var = sqs[c] / n - mean * mean;
    x[idx] = (x[idx] - mean) * rsqrtf(var + EPS_BN) * g[c] + b[c];
}

// ---------------- launch ----------------
extern "C" void kernel_launch(void* const* d_in, const int* in_sizes, int n_in,
                              void* d_out, int out_size, void* d_ws, size_t ws_size,
                              hipStream_t stream) {
    const float* x   = (const float*)d_in[0];
    const int*   ei  = (const int*)d_in[1];
    const float* W1  = (const float*)d_in[2];
    const float* as1 = (const float*)d_in[3];
    const float* ad1 = (const float*)d_in[4];
    const float* b1  = (const float*)d_in[5];
    const float* g1  = (const float*)d_in[6];
    const float* be1 = (const float*)d_in[7];
    const float* W2  = (const float*)d_in[8];
    const float* as2 = (const float*)d_in[9];
    const float* ad2 = (const float*)d_in[10];
    const float* b2  = (const float*)d_in[11];
    const float* g2  = (const float*)d_in[12];
    const float* be2 = (const float*)d_in[13];
    const float* W3  = (const float*)d_in[14];
    const float* as3 = (const float*)d_in[15];
    const float* ad3 = (const float*)d_in[16];
    const float* b3  = (const float*)d_in[17];
    const float* lw  = (const float*)d_in[18];
    const float* lb  = (const float*)d_in[19];
    float* outp = (float*)d_out;

    const int n = in_sizes[0] / 128;  // 50000
    const int e = in_sizes[1] / 2;    // 800000

    // workspace layout
    char* w = (char*)d_ws;
    size_t off = 0;
    auto alloc = [&](size_t bytes) -> void* {
        void* p = w + off;
        off += (bytes + 255) & ~(size_t)255;
        return p;
    };
    __bf16* xhb  = (__bf16*)alloc((size_t)n * 256 * 2);   // bf16 GEMM output
    float* bufA  = (float*)alloc((size_t)n * 128 * 4);    // layer-2 agg output
    float* bufB  = (float*)alloc((size_t)n * 256 * 4);    // layer-1/3 agg output
    float* asrc  = (float*)alloc((size_t)n * 2 * 4);
    float* adst  = (float*)alloc((size_t)n * 2 * 4);
    float* bnstat = (float*)alloc(512 * 4);  // sums [0..255], sqs [256..511]
    int* deg    = (int*)alloc((size_t)n * 4);
    int* excl   = (int*)alloc((size_t)n * 4);
    int* rowptr = (int*)alloc((size_t)(n + 1) * 4);
    int* fill   = (int*)alloc((size_t)n * 4);
    int* colb   = (int*)alloc((size_t)e * 4);
    int* bsum   = (int*)alloc(64 * 4);
    int* dcnt   = (int*)alloc(64 * 4);
    __bf16* Wb1 = (__bf16*)alloc(256 * 128 * 2);  // [M=256][K=128]
    __bf16* Wb2 = (__bf16*)alloc(128 * 256 * 2);  // [M=128][K=256]
    __bf16* Wb3 = (__bf16*)alloc(128 * 128 * 2);  // [M=128][K=128]

    const int nb1 = (n + 1023) / 1024;

    // edge dtype detect
    hipMemsetAsync(dcnt, 0, 4, stream);
    k_detect<<<4, 256, 0, stream>>>(ei, dcnt, e);

    // CSR
    hipMemsetAsync(deg, 0, (size_t)n * 4, stream);
    k_hist<<<(e + 255) / 256, 256, 0, stream>>>(ei, dcnt, deg, e);
    k_scan1<<<nb1, 1024, 0, stream>>>(deg, excl, bsum, n);
    k_scan2<<<1, 1, 0, stream>>>(bsum, nb1);
    k_scan3<<<(n + 255) / 256, 256, 0, stream>>>(excl, bsum, rowptr, n, e);
    hipMemsetAsync(fill, 0, (size_t)n * 4, stream);
    k_scatter<<<(e + 255) / 256, 256, 0, stream>>>(ei, dcnt, rowptr, fill, colb, e);

    // weight convert (can overlap CSR epoch; same stream anyway)
    k_wconv<<<(256 * 128 + 255) / 256, 256, 0, stream>>>(W1, Wb1, 7, 256, 256 * 128);
    k_wconv<<<(128 * 256 + 255) / 256, 256, 0, stream>>>(W2, Wb2, 8, 128, 128 * 256);
    k_wconv<<<(128 * 128 + 255) / 256, 256, 0, stream>>>(W3, Wb3, 7, 128, 128 * 128);

    const int nwb = (n + 3) / 4;  // wave-per-node blocks (4 waves/block)
    const int nrow = (n + 63) / 64;

    // ---- layer 1: 128 -> 2x128 ----
    k_gemm_mfma<128><<<dim3(256 / 64, nrow), 256, 0, stream>>>(x, Wb1, xhb, n, 256);
    k_attn<128><<<nwb, 256, 0, stream>>>(xhb, as1, ad1, asrc, adst, n);
    k_agg<128><<<nwb, 256, 0, stream>>>(xhb, asrc, adst, rowptr, colb, b1, bufB, n);
    hipMemsetAsync(bnstat, 0, 512 * 4, stream);
    k_bn_stats<<<256, 256, 0, stream>>>(bufB, bnstat, bnstat + 256, n, 256);
    k_bn_norm<<<((size_t)n * 256 + 255) / 256, 256, 0, stream>>>(bufB, bnstat, bnstat + 256, g1, be1, n, 256);

    // ---- layer 2: 256 -> 2x64 ----
    k_gemm_mfma<256><<<dim3(128 / 64, nrow), 256, 0, stream>>>(bufB, Wb2, xhb, n, 128);
    k_attn<64><<<nwb, 256, 0, stream>>>(xhb, as2, ad2, asrc, adst, n);
    k_agg<64><<<nwb, 256, 0, stream>>>(xhb, asrc, adst, rowptr, colb, b2, bufA, n);
    hipMemsetAsync(bnstat, 0, 512 * 4, stream);
    k_bn_stats<<<256, 128, 0, stream>>>(bufA, bnstat, bnstat + 256, n, 128);
    k_bn_norm<<<((size_t)n * 128 + 255) / 256, 256, 0, stream>>>(bufA, bnstat, bnstat + 256, g2, be2, n, 128);

    // ---- layer 3: 128 -> 2x64 ----
    k_gemm_mfma<128><<<dim3(128 / 64, nrow), 256, 0, stream>>>(bufA, Wb3, xhb, n, 128);
    k_attn<64><<<nwb, 256, 0, stream>>>(xhb, as3, ad3, asrc, adst, n);
    k_agg<64><<<nwb, 256, 0, stream>>>(xhb, asrc, adst, rowptr, colb, b3, bufB, n);

    // ---- final linear: [n,128] @ [128,64] + lb (fp32) ----
    k_gemm<<<dim3(1, nrow), 256, 0, stream>>>(bufB, lw, outp, lb, n, 128, 64);
}

// Round 5
// 624.270 us; speedup vs baseline: 1.2930x; 1.0646x over previous
//
#include <hip/hip_runtime.h>
#include <hip/hip_bf16.h>

#define NEG_SLOPE 0.2f
#define EPS_BN 1e-5f
#define EPS_SM 1e-16f

typedef __bf16 bf16x8 __attribute__((ext_vector_type(8)));
typedef __bf16 bf16x4 __attribute__((ext_vector_type(4)));
typedef float floatx4 __attribute__((ext_vector_type(4)));

__device__ __forceinline__ float leaky(float x) { return x > 0.f ? x : NEG_SLOPE * x; }

// ---------------- edge dtype detection (int32 vs int64 layout) ----------------
__global__ void k_detect(const int* __restrict__ ei, int* __restrict__ cnt, int e) {
    int i = threadIdx.x + blockIdx.x * blockDim.x;
    if (i < 1024 && 2 * i + 1 < 2 * e) {
        if (ei[2 * i + 1] != 0) atomicAdd(cnt, 1);
    }
}

// ---------------- CSR build ----------------
__global__ void k_hist(const int* __restrict__ ei, const int* __restrict__ cnt,
                       int* __restrict__ deg, int e) {
    int g = threadIdx.x + blockIdx.x * blockDim.x;
    if (g >= e) return;
    bool is64 = (*cnt) < 512;
    int d = is64 ? ei[2 * (e + g)] : ei[e + g];
    atomicAdd(&deg[d], 1);
}

__global__ __launch_bounds__(1024) void k_scan1(const int* __restrict__ deg,
                                                int* __restrict__ excl,
                                                int* __restrict__ bsum, int n) {
    __shared__ int sm[1024];
    int tid = threadIdx.x;
    int g = blockIdx.x * 1024 + tid;
    int v = (g < n) ? deg[g] : 0;
    sm[tid] = v;
    __syncthreads();
    for (int off = 1; off < 1024; off <<= 1) {
        int t = (tid >= off) ? sm[tid - off] : 0;
        __syncthreads();
        sm[tid] += t;
        __syncthreads();
    }
    if (g < n) excl[g] = sm[tid] - v;
    if (tid == 1023) bsum[blockIdx.x] = sm[1023];
}

__global__ void k_scan2(int* bsum, int nb) {
    if (threadIdx.x == 0 && blockIdx.x == 0) {
        int acc = 0;
        for (int i = 0; i < nb; ++i) { int v = bsum[i]; bsum[i] = acc; acc += v; }
    }
}

__global__ void k_scan3(const int* __restrict__ excl, const int* __restrict__ bsum,
                        int* __restrict__ rowptr, int n, int e) {
    int g = threadIdx.x + blockIdx.x * blockDim.x;
    if (g < n) rowptr[g] = excl[g] + bsum[g >> 10];
    if (g == 0) rowptr[n] = e;
}

__global__ void k_scatter(const int* __restrict__ ei, const int* __restrict__ cnt,
                          const int* __restrict__ rowptr, int* __restrict__ fill,
                          int* __restrict__ col, int e) {
    int g = threadIdx.x + blockIdx.x * blockDim.x;
    if (g >= e) return;
    bool is64 = (*cnt) < 512;
    int s = is64 ? ei[2 * g] : ei[g];
    int d = is64 ? ei[2 * (e + g)] : ei[e + g];
    int pos = rowptr[d] + atomicAdd(&fill[d], 1);
    col[pos] = s;
}

// ---------------- weight convert+transpose: Wb[m][k] = bf16(W[k][m]) ----------------
__global__ void k_wconv(const float* __restrict__ W, __bf16* __restrict__ Wb,
                        int kshift, int M, int total) {
    int idx = threadIdx.x + blockIdx.x * blockDim.x;
    if (idx >= total) return;
    int mm = idx >> kshift;
    int kk = idx & ((1 << kshift) - 1);
    Wb[idx] = (__bf16)W[(size_t)kk * M + mm];
}

// ---------------- bn scale/shift prep ----------------
__global__ void k_bn_prep(const float* __restrict__ sums, const float* __restrict__ sqs,
                          const float* __restrict__ g, const float* __restrict__ b,
                          float* __restrict__ scale, float* __restrict__ shift,
                          int n, int f) {
    int c = threadIdx.x;
    if (c >= f) return;
    float mean = sums[c] / n;
    float var = sqs[c] / n - mean * mean;
    float sc = g[c] * rsqrtf(var + EPS_BN);
    scale[c] = sc;
    shift[c] = b[c] - mean * sc;
}

// ---- bf16 MFMA GEMM (128-row tile): Cb[n,M](bf16) = affine(A)[n,K](f32) @ Bt[M,K]^T ----
template <int K>
__global__ __launch_bounds__(256) void k_gemm_mfma(const float* __restrict__ A,
                                                   const __bf16* __restrict__ Bt,
                                                   __bf16* __restrict__ Cb,
                                                   int n, int M,
                                                   const float* __restrict__ scale,
                                                   const float* __restrict__ shift) {
    __shared__ __align__(16) __bf16 As[128][72];
    __shared__ __align__(16) __bf16 Bs[64][72];
    const int row0 = blockIdx.y * 128, col0 = blockIdx.x * 64;
    const int lane = threadIdx.x & 63, w = threadIdx.x >> 6;
    const int m = lane & 15, quad = lane >> 4;
    floatx4 acc[2][4];
#pragma unroll
    for (int i = 0; i < 2; ++i)
#pragma unroll
        for (int j = 0; j < 4; ++j) acc[i][j] = (floatx4)0.f;

    const int sra = threadIdx.x >> 1;        // 0..127
    const int ska = (threadIdx.x & 1) * 32;  // 0,32
    const int srb = threadIdx.x >> 2;        // 0..63
    const int skb = (threadIdx.x & 3) * 16;  // 0,16,32,48

    for (int kc = 0; kc < K; kc += 64) {
        // stage A (fp32 -> bf16, optional BN affine)
        {
            int grow = row0 + sra;
            if (grow < n) {
                const float* p = A + (size_t)grow * K + kc + ska;
#pragma unroll
                for (int q = 0; q < 8; ++q) {
                    float4 v = *reinterpret_cast<const float4*>(p + q * 4);
                    if (scale) {
                        int c = kc + ska + q * 4;
                        float4 sc = *reinterpret_cast<const float4*>(scale + c);
                        float4 sh = *reinterpret_cast<const float4*>(shift + c);
                        v.x = v.x * sc.x + sh.x; v.y = v.y * sc.y + sh.y;
                        v.z = v.z * sc.z + sh.z; v.w = v.w * sc.w + sh.w;
                    }
                    bf16x4 cv = {(__bf16)v.x, (__bf16)v.y, (__bf16)v.z, (__bf16)v.w};
                    *reinterpret_cast<bf16x4*>(&As[sra][ska + q * 4]) = cv;
                }
            } else {
#pragma unroll
                for (int q = 0; q < 8; ++q)
                    *reinterpret_cast<bf16x4*>(&As[sra][ska + q * 4]) = (bf16x4)(__bf16)0.f;
            }
        }
        // stage B (bf16 [M][K], straight copy)
        {
            const __bf16* p = Bt + (size_t)(col0 + srb) * K + kc + skb;
            bf16x8 b0 = *reinterpret_cast<const bf16x8*>(p);
            bf16x8 b1 = *reinterpret_cast<const bf16x8*>(p + 8);
            *reinterpret_cast<bf16x8*>(&Bs[srb][skb]) = b0;
            *reinterpret_cast<bf16x8*>(&Bs[srb][skb + 8]) = b1;
        }
        __syncthreads();
#pragma unroll
        for (int ks = 0; ks < 64; ks += 32) {
            bf16x8 a0 = *reinterpret_cast<const bf16x8*>(&As[w * 32 + m][ks + quad * 8]);
            bf16x8 a1 = *reinterpret_cast<const bf16x8*>(&As[w * 32 + 16 + m][ks + quad * 8]);
#pragma unroll
            for (int nt = 0; nt < 4; ++nt) {
                bf16x8 b = *reinterpret_cast<const bf16x8*>(&Bs[nt * 16 + m][ks + quad * 8]);
                acc[0][nt] = __builtin_amdgcn_mfma_f32_16x16x32_bf16(a0, b, acc[0][nt], 0, 0, 0);
                acc[1][nt] = __builtin_amdgcn_mfma_f32_16x16x32_bf16(a1, b, acc[1][nt], 0, 0, 0);
            }
        }
        __syncthreads();
    }
#pragma unroll
    for (int mt = 0; mt < 2; ++mt) {
#pragma unroll
        for (int nt = 0; nt < 4; ++nt) {
#pragma unroll
            for (int r = 0; r < 4; ++r) {
                int row = row0 + w * 32 + mt * 16 + quad * 4 + r;
                if (row < n) Cb[(size_t)row * M + col0 + nt * 16 + m] = (__bf16)acc[mt][nt][r];
            }
        }
    }
}

// ---- final linear via MFMA: out[n,64](f32) = A[n,128] @ lw[128,64] + lb
//      A exact via hi/lo bf16 split (2 MFMA terms), lw rounded once to bf16.
//      FIX(R5): LDS tiles must hold K=128 -> [64][136] (R3/R4 had [64][72] = OOB stomp).
__global__ __launch_bounds__(256) void k_lin(const float* __restrict__ A,
                                             const float* __restrict__ lw,
                                             const float* __restrict__ lb,
                                             float* __restrict__ out, int n) {
    __shared__ __align__(16) __bf16 Ahi[64][136];
    __shared__ __align__(16) __bf16 Alo[64][136];
    __shared__ __align__(16) __bf16 Bhi[64][136];
    const int row0 = blockIdx.y * 64;
    const int lane = threadIdx.x & 63, w = threadIdx.x >> 6;
    const int m = lane & 15, quad = lane >> 4;
    floatx4 acc[4];
#pragma unroll
    for (int i = 0; i < 4; ++i) acc[i] = (floatx4)0.f;

    // stage A: 64 rows x 128 K, hi/lo split
    {
        int sr = threadIdx.x >> 2, sk0 = (threadIdx.x & 3) * 32;
        int grow = row0 + sr;
#pragma unroll
        for (int q = 0; q < 8; ++q) {
            float4 v = make_float4(0.f, 0.f, 0.f, 0.f);
            if (grow < n) v = *reinterpret_cast<const float4*>(A + (size_t)grow * 128 + sk0 + q * 4);
            float vv[4] = {v.x, v.y, v.z, v.w};
#pragma unroll
            for (int i = 0; i < 4; ++i) {
                __bf16 h = (__bf16)vv[i];
                Ahi[sr][sk0 + q * 4 + i] = h;
                Alo[sr][sk0 + q * 4 + i] = (__bf16)(vv[i] - (float)h);
            }
        }
    }
    // stage B transposed: Bhi[m][k] = bf16(lw[k][m]), m in 0..63, k in 0..127
    {
        int k0 = threadIdx.x >> 1, m0 = (threadIdx.x & 1) * 32;
#pragma unroll
        for (int q = 0; q < 8; ++q) {
            float4 v = *reinterpret_cast<const float4*>(lw + (size_t)k0 * 64 + m0 + q * 4);
            float vv[4] = {v.x, v.y, v.z, v.w};
#pragma unroll
            for (int i = 0; i < 4; ++i) Bhi[m0 + q * 4 + i][k0] = (__bf16)vv[i];
        }
    }
    __syncthreads();
#pragma unroll
    for (int ks = 0; ks < 128; ks += 32) {
        bf16x8 ah = *reinterpret_cast<const bf16x8*>(&Ahi[w * 16 + m][ks + quad * 8]);
        bf16x8 al = *reinterpret_cast<const bf16x8*>(&Alo[w * 16 + m][ks + quad * 8]);
#pragma unroll
        for (int nt = 0; nt < 4; ++nt) {
            bf16x8 bh = *reinterpret_cast<const bf16x8*>(&Bhi[nt * 16 + m][ks + quad * 8]);
            acc[nt] = __builtin_amdgcn_mfma_f32_16x16x32_bf16(ah, bh, acc[nt], 0, 0, 0);
            acc[nt] = __builtin_amdgcn_mfma_f32_16x16x32_bf16(al, bh, acc[nt], 0, 0, 0);
        }
    }
#pragma unroll
    for (int nt = 0; nt < 4; ++nt) {
#pragma unroll
        for (int r = 0; r < 4; ++r) {
            int row = row0 + w * 16 + quad * 4 + r;
            int c = nt * 16 + m;
            if (row < n) out[(size_t)row * 64 + c] = acc[nt][r] + lb[c];
        }
    }
}

// ---------------- attention coefficients: a_src/a_dst [n,2] (bf16 xh) -------------
template <int C>
__global__ __launch_bounds__(256) void k_attn(const __bf16* __restrict__ xh,
                                              const float* __restrict__ att_s,
                                              const float* __restrict__ att_d,
                                              float* __restrict__ asrc,
                                              float* __restrict__ adst, int n) {
    constexpr int VEC = (2 * C) / 64;
    int wave = (blockIdx.x * blockDim.x + threadIdx.x) >> 6;
    int lane = threadIdx.x & 63;
    if (wave >= n) return;
    const __bf16* row = xh + (size_t)wave * (2 * C) + lane * VEC;
    float ps = 0.f, pd = 0.f;
#pragma unroll
    for (int q = 0; q < VEC; ++q) {
        float v = (float)row[q];
        ps += v * att_s[lane * VEC + q];
        pd += v * att_d[lane * VEC + q];
    }
#pragma unroll
    for (int off = 1; off <= 16; off <<= 1) {
        ps += __shfl_xor(ps, off);
        pd += __shfl_xor(pd, off);
    }
    if ((lane & 31) == 0) {
        int h = lane >> 5;
        asrc[2 * wave + h] = ps;
        adst[2 * wave + h] = pd;
    }
}

// ---------------- GAT aggregation (segment softmax + multi-edge bf16x8 gather) ------
template <int C>
__global__ __launch_bounds__(256) void k_agg(const __bf16* __restrict__ xh,
                                             const float* __restrict__ asrc,
                                             const float* __restrict__ adst,
                                             const int* __restrict__ rowptr,
                                             const int* __restrict__ col,
                                             const float* __restrict__ bias,
                                             float* __restrict__ out, int n) {
    constexpr int F = 2 * C;        // bf16 per row
    constexpr int G = F / 8;        // lanes per edge-group (32 or 16)
    constexpr int NG = 64 / G;      // concurrent edges (2 or 4)
    constexpr int GSH = (G == 32) ? 5 : 4;
    int wave = (blockIdx.x * blockDim.x + threadIdx.x) >> 6;
    int lane = threadIdx.x & 63;
    if (wave >= n) return;
    const int i = wave;
    const int t = lane & (G - 1);
    const int g = lane >> GSH;
    const bool h1 = (t * 8) >= C;   // head of this lane's 8 channels (receiver-side)
    const int beg = rowptr[i];
    const int deg = rowptr[i + 1] - beg;
    const float2 adv = *reinterpret_cast<const float2*>(adst + 2 * i);
    const float2 asv = *reinterpret_cast<const float2*>(asrc + 2 * i);
    const float es0 = leaky(asv.x + adv.x), es1 = leaky(asv.y + adv.y);
    float m0 = es0, m1 = es1;
    for (int j = lane; j < deg; j += 64) {
        int s = col[beg + j];
        float2 av = *reinterpret_cast<const float2*>(asrc + 2 * s);
        m0 = fmaxf(m0, leaky(av.x + adv.x));
        m1 = fmaxf(m1, leaky(av.y + adv.y));
    }
#pragma unroll
    for (int off = 1; off <= 32; off <<= 1) {
        m0 = fmaxf(m0, __shfl_xor(m0, off));
        m1 = fmaxf(m1, __shfl_xor(m1, off));
    }
    float acc[8] = {};
    float d0 = 0.f, d1 = 0.f;
    for (int base = 0; base < deg; base += 64) {
        int cnt = min(64, deg - base);
        float ex0 = 0.f, ex1 = 0.f;
        int s = 0;
        if (lane < cnt) {
            s = col[beg + base + lane];
            float2 av = *reinterpret_cast<const float2*>(asrc + 2 * s);
            ex0 = expf(leaky(av.x + adv.x) - m0);
            ex1 = expf(leaky(av.y + adv.y) - m1);
        }
        d0 += ex0; d1 += ex1;
        int iters = (cnt + NG - 1) >> (NG == 2 ? 1 : 2);
        for (int kk = 0; kk < iters; kk += 2) {
            int j0 = kk * NG + g;
            int j1 = j0 + NG;
            // shfl BOTH heads' weights; select with the RECEIVER's head.
            // (ex* are zero on lanes >= cnt, so j0-overrun weights vanish naturally.)
            float w0a = __shfl(ex0, j0);
            float w0b = __shfl(ex1, j0);
            int sj0 = __shfl(s, j0);
            float w1a = __shfl(ex0, j1 & 63);
            float w1b = __shfl(ex1, j1 & 63);
            int sj1 = __shfl(s, j1 & 63);
            float w0 = h1 ? w0b : w0a;
            float w1 = h1 ? w1b : w1a;
            if (j1 >= cnt) w1 = 0.f;
            const __bf16* p0 = xh + (size_t)sj0 * F + t * 8;
            const __bf16* p1 = xh + (size_t)sj1 * F + t * 8;
            bf16x8 v0 = *reinterpret_cast<const bf16x8*>(p0);
            bf16x8 v1 = *reinterpret_cast<const bf16x8*>(p1);
#pragma unroll
            for (int q = 0; q < 8; ++q) acc[q] += w0 * (float)v0[q];
#pragma unroll
            for (int q = 0; q < 8; ++q) acc[q] += w1 * (float)v1[q];
        }
    }
    // combine edge-groups (each group has full channel coverage)
#pragma unroll
    for (int q = 0; q < 8; ++q) {
#pragma unroll
        for (int off = G; off < 64; off <<= 1) acc[q] += __shfl_xor(acc[q], off);
    }
#pragma unroll
    for (int off = 1; off <= 32; off <<= 1) {
        d0 += __shfl_xor(d0, off);
        d1 += __shfl_xor(d1, off);
    }
    // self loop (post-combine: add exactly once per lane)
    float exs0 = expf(es0 - m0), exs1 = expf(es1 - m1);
    d0 += exs0; d1 += exs1;
    {
        float ws = h1 ? exs1 : exs0;
        bf16x8 v = *reinterpret_cast<const bf16x8*>(xh + (size_t)i * F + t * 8);
#pragma unroll
        for (int q = 0; q < 8; ++q) acc[q] += ws * (float)v[q];
    }
    float inv = 1.0f / ((h1 ? d1 : d0) + EPS_SM);
    float o[8];
#pragma unroll
    for (int q = 0; q < 8; ++q) o[q] = fmaxf(acc[q] * inv + bias[t * 8 + q], 0.f);
    float* po = out + (size_t)i * F + t * 8;
    if (g == 0) *reinterpret_cast<float4*>(po) = make_float4(o[0], o[1], o[2], o[3]);
    else if (g == 1) *reinterpret_cast<float4*>(po + 4) = make_float4(o[4], o[5], o[6], o[7]);
}

// ---------------- BatchNorm stats ----------------
__global__ void k_bn_stats(const float* __restrict__ x, float* __restrict__ sums,
                           float* __restrict__ sqs, int n, int f) {
    int c = threadIdx.x;  // blockDim.x == f
    float s = 0.f, q = 0.f;
    for (int r = blockIdx.x; r < n; r += gridDim.x) {
        float v = x[(size_t)r * f + c];
        s += v; q += v * v;
    }
    atomicAdd(&sums[c], s);
    atomicAdd(&sqs[c], q);
}

// ---------------- launch ----------------
extern "C" void kernel_launch(void* const* d_in, const int* in_sizes, int n_in,
                              void* d_out, int out_size, void* d_ws, size_t ws_size,
                              hipStream_t stream) {
    const float* x   = (const float*)d_in[0];
    const int*   ei  = (const int*)d_in[1];
    const float* W1  = (const float*)d_in[2];
    const float* as1 = (const float*)d_in[3];
    const float* ad1 = (const float*)d_in[4];
    const float* b1  = (const float*)d_in[5];
    const float* g1  = (const float*)d_in[6];
    const float* be1 = (const float*)d_in[7];
    const float* W2  = (const float*)d_in[8];
    const float* as2 = (const float*)d_in[9];
    const float* ad2 = (const float*)d_in[10];
    const float* b2  = (const float*)d_in[11];
    const float* g2  = (const float*)d_in[12];
    const float* be2 = (const float*)d_in[13];
    const float* W3  = (const float*)d_in[14];
    const float* as3 = (const float*)d_in[15];
    const float* ad3 = (const float*)d_in[16];
    const float* b3  = (const float*)d_in[17];
    const float* lw  = (const float*)d_in[18];
    const float* lb  = (const float*)d_in[19];
    float* outp = (float*)d_out;

    const int n = in_sizes[0] / 128;  // 50000
    const int e = in_sizes[1] / 2;    // 800000

    // workspace layout
    char* w = (char*)d_ws;
    size_t off = 0;
    auto alloc = [&](size_t bytes) -> void* {
        void* p = w + off;
        off += (bytes + 255) & ~(size_t)255;
        return p;
    };
    __bf16* xhb  = (__bf16*)alloc((size_t)n * 256 * 2);
    float* bufA  = (float*)alloc((size_t)n * 128 * 4);
    float* bufB  = (float*)alloc((size_t)n * 256 * 4);
    float* asrc  = (float*)alloc((size_t)n * 2 * 4);
    float* adst  = (float*)alloc((size_t)n * 2 * 4);
    int* excl    = (int*)alloc((size_t)n * 4);
    int* rowptr  = (int*)alloc((size_t)(n + 1) * 4);
    int* colb    = (int*)alloc((size_t)e * 4);
    int* bsum    = (int*)alloc(64 * 4);
    float* sc1   = (float*)alloc(256 * 4);
    float* sh1   = (float*)alloc(256 * 4);
    float* sc2   = (float*)alloc(128 * 4);
    float* sh2   = (float*)alloc(128 * 4);
    __bf16* Wb1  = (__bf16*)alloc(256 * 128 * 2);
    __bf16* Wb2  = (__bf16*)alloc(128 * 256 * 2);
    __bf16* Wb3  = (__bf16*)alloc(128 * 128 * 2);
    // ---- contiguous zero block ----
    char* zb_begin = (char*)(w + off);
    int* deg     = (int*)alloc((size_t)n * 4);
    int* fill    = (int*)alloc((size_t)n * 4);
    float* bn1   = (float*)alloc(512 * 4);  // L1 sums/sqs
    float* bn2   = (float*)alloc(512 * 4);  // L2 sums/sqs
    int* dcnt    = (int*)alloc(256);
    char* zb_end = (char*)(w + off);

    const int nb1 = (n + 1023) / 1024;

    hipMemsetAsync(zb_begin, 0, (size_t)(zb_end - zb_begin), stream);

    // edge dtype detect + CSR
    k_detect<<<4, 256, 0, stream>>>(ei, dcnt, e);
    k_hist<<<(e + 255) / 256, 256, 0, stream>>>(ei, dcnt, deg, e);
    k_scan1<<<nb1, 1024, 0, stream>>>(deg, excl, bsum, n);
    k_scan2<<<1, 1, 0, stream>>>(bsum, nb1);
    k_scan3<<<(n + 255) / 256, 256, 0, stream>>>(excl, bsum, rowptr, n, e);
    k_scatter<<<(e + 255) / 256, 256, 0, stream>>>(ei, dcnt, rowptr, fill, colb, e);

    // weight convert
    k_wconv<<<(256 * 128 + 255) / 256, 256, 0, stream>>>(W1, Wb1, 7, 256, 256 * 128);
    k_wconv<<<(128 * 256 + 255) / 256, 256, 0, stream>>>(W2, Wb2, 8, 128, 128 * 256);
    k_wconv<<<(128 * 128 + 255) / 256, 256, 0, stream>>>(W3, Wb3, 7, 128, 128 * 128);

    const int nwb = (n + 3) / 4;       // wave-per-node blocks (4 waves/block)
    const int nrow = (n + 127) / 128;  // gemm row blocks

    // ---- layer 1: 128 -> 2x128 ----
    k_gemm_mfma<128><<<dim3(4, nrow), 256, 0, stream>>>(x, Wb1, xhb, n, 256, nullptr, nullptr);
    k_attn<128><<<nwb, 256, 0, stream>>>(xhb, as1, ad1, asrc, adst, n);
    k_agg<128><<<nwb, 256, 0, stream>>>(xhb, asrc, adst, rowptr, colb, b1, bufB, n);
    k_bn_stats<<<256, 256, 0, stream>>>(bufB, bn1, bn1 + 256, n, 256);
    k_bn_prep<<<1, 256, 0, stream>>>(bn1, bn1 + 256, g1, be1, sc1, sh1, n, 256);

    // ---- layer 2: 256 -> 2x64 (BN1 fused into A-staging) ----
    k_gemm_mfma<256><<<dim3(2, nrow), 256, 0, stream>>>(bufB, Wb2, xhb, n, 128, sc1, sh1);
    k_attn<64><<<nwb, 256, 0, stream>>>(xhb, as2, ad2, asrc, adst, n);
    k_agg<64><<<nwb, 256, 0, stream>>>(xhb, asrc, adst, rowptr, colb, b2, bufA, n);
    k_bn_stats<<<256, 128, 0, stream>>>(bufA, bn2, bn2 + 256, n, 128);
    k_bn_prep<<<1, 256, 0, stream>>>(bn2, bn2 + 256, g2, be2, sc2, sh2, n, 128);

    // ---- layer 3: 128 -> 2x64 (BN2 fused) ----
    k_gemm_mfma<128><<<dim3(2, nrow), 256, 0, stream>>>(bufA, Wb3, xhb, n, 128, sc2, sh2);
    k_attn<64><<<nwb, 256, 0, stream>>>(xhb, as3, ad3, asrc, adst, n);
    k_agg<64><<<nwb, 256, 0, stream>>>(xhb, asrc, adst, rowptr, colb, b3, bufB, n);

    // ---- final linear: [n,128] @ [128,64] + lb (MFMA, A hi/lo split, fp32 out) ----
    k_lin<<<dim3(1, (n + 63) / 64), 256, 0, stream>>>(bufB, lw, lb, outp, n);
}

// Round 6
// 533.518 us; speedup vs baseline: 1.5130x; 1.1701x over previous
//
#include <hip/hip_runtime.h>
#include <hip/hip_bf16.h>

#define NEG_SLOPE 0.2f
#define EPS_BN 1e-5f
#define EPS_SM 1e-16f

typedef __bf16 bf16x8 __attribute__((ext_vector_type(8)));
typedef __bf16 bf16x4 __attribute__((ext_vector_type(4)));
typedef __bf16 bf16x2 __attribute__((ext_vector_type(2)));
typedef float floatx4 __attribute__((ext_vector_type(4)));

__device__ __forceinline__ float leaky(float x) { return x > 0.f ? x : NEG_SLOPE * x; }

// ---------------- edge dtype detection (int32 vs int64 layout) ----------------
__global__ void k_detect(const int* __restrict__ ei, int* __restrict__ cnt, int e) {
    int i = threadIdx.x + blockIdx.x * blockDim.x;
    if (i < 1024 && 2 * i + 1 < 2 * e) {
        if (ei[2 * i + 1] != 0) atomicAdd(cnt, 1);
    }
}

// ---------------- CSR build ----------------
__global__ void k_hist(const int* __restrict__ ei, const int* __restrict__ cnt,
                       int* __restrict__ deg, int e) {
    int g = threadIdx.x + blockIdx.x * blockDim.x;
    if (g >= e) return;
    bool is64 = (*cnt) < 512;
    int d = is64 ? ei[2 * (e + g)] : ei[e + g];
    atomicAdd(&deg[d], 1);
}

__global__ __launch_bounds__(1024) void k_scan1(const int* __restrict__ deg,
                                                int* __restrict__ excl,
                                                int* __restrict__ bsum, int n) {
    __shared__ int sm[1024];
    int tid = threadIdx.x;
    int g = blockIdx.x * 1024 + tid;
    int v = (g < n) ? deg[g] : 0;
    sm[tid] = v;
    __syncthreads();
    for (int off = 1; off < 1024; off <<= 1) {
        int t = (tid >= off) ? sm[tid - off] : 0;
        __syncthreads();
        sm[tid] += t;
        __syncthreads();
    }
    if (g < n) excl[g] = sm[tid] - v;
    if (tid == 1023) bsum[blockIdx.x] = sm[1023];
}

__global__ void k_scan2(int* bsum, int nb) {
    if (threadIdx.x == 0 && blockIdx.x == 0) {
        int acc = 0;
        for (int i = 0; i < nb; ++i) { int v = bsum[i]; bsum[i] = acc; acc += v; }
    }
}

__global__ void k_scan3(const int* __restrict__ excl, const int* __restrict__ bsum,
                        int* __restrict__ rowptr, int n, int e) {
    int g = threadIdx.x + blockIdx.x * blockDim.x;
    if (g < n) rowptr[g] = excl[g] + bsum[g >> 10];
    if (g == 0) rowptr[n] = e;
}

__global__ void k_scatter(const int* __restrict__ ei, const int* __restrict__ cnt,
                          const int* __restrict__ rowptr, int* __restrict__ fill,
                          int* __restrict__ col, int e) {
    int g = threadIdx.x + blockIdx.x * blockDim.x;
    if (g >= e) return;
    bool is64 = (*cnt) < 512;
    int s = is64 ? ei[2 * g] : ei[g];
    int d = is64 ? ei[2 * (e + g)] : ei[e + g];
    int pos = rowptr[d] + atomicAdd(&fill[d], 1);
    col[pos] = s;
}

// ---------------- weight convert+transpose: Wb[m][k] = bf16(W[k][m]) ----------------
__global__ void k_wconv(const float* __restrict__ W, __bf16* __restrict__ Wb,
                        int kshift, int M, int total) {
    int idx = threadIdx.x + blockIdx.x * blockDim.x;
    if (idx >= total) return;
    int mm = idx >> kshift;
    int kk = idx & ((1 << kshift) - 1);
    Wb[idx] = (__bf16)W[(size_t)kk * M + mm];
}

// ---------------- bn scale/shift prep ----------------
__global__ void k_bn_prep(const float* __restrict__ sums, const float* __restrict__ sqs,
                          const float* __restrict__ g, const float* __restrict__ b,
                          float* __restrict__ scale, float* __restrict__ shift,
                          int n, int f) {
    int c = threadIdx.x;
    if (c >= f) return;
    float mean = sums[c] / n;
    float var = sqs[c] / n - mean * mean;
    float sc = g[c] * rsqrtf(var + EPS_BN);
    scale[c] = sc;
    shift[c] = b[c] - mean * sc;
}

// ---- bf16 MFMA GEMM, 128x128 tile, fused BN-affine on A + fused attn dots epilogue.
//      Cb[n,M](bf16) = affine(A)[n,K] @ Bt[M,K]^T ; asrc/adst += per-head dots (atomics).
template <int K, int LC, bool BF16IN>
__global__ __launch_bounds__(256) void k_gemm(const void* __restrict__ Ain,
                                              const __bf16* __restrict__ Bt,
                                              __bf16* __restrict__ Cb, int n, int M,
                                              const float* __restrict__ scale,
                                              const float* __restrict__ shift,
                                              const float* __restrict__ att_s,
                                              const float* __restrict__ att_d,
                                              float* __restrict__ asrc,
                                              float* __restrict__ adst) {
    __shared__ __align__(16) __bf16 As[128][72];
    __shared__ __align__(16) __bf16 Bs[128][72];
    const int row0 = blockIdx.y * 128, col0 = blockIdx.x * 128;
    const int lane = threadIdx.x & 63, w = threadIdx.x >> 6;
    const int m = lane & 15, quad = lane >> 4;
    floatx4 acc[2][8];
#pragma unroll
    for (int i = 0; i < 2; ++i)
#pragma unroll
        for (int j = 0; j < 8; ++j) acc[i][j] = (floatx4)0.f;

    const int sr = threadIdx.x >> 1;        // 0..127
    const int sk = (threadIdx.x & 1) * 32;  // 0,32

    for (int kc = 0; kc < K; kc += 64) {
        // ---- stage A ----
        {
            int grow = row0 + sr;
            if (grow < n) {
                if (BF16IN) {
                    const __bf16* p = (const __bf16*)Ain + (size_t)grow * K + kc + sk;
#pragma unroll
                    for (int q = 0; q < 4; ++q) {
                        bf16x8 vv = *reinterpret_cast<const bf16x8*>(p + q * 8);
                        if (scale) {
                            const float* scp = scale + kc + sk + q * 8;
                            const float* shp = shift + kc + sk + q * 8;
                            bf16x8 r;
#pragma unroll
                            for (int e2 = 0; e2 < 8; ++e2)
                                r[e2] = (__bf16)((float)vv[e2] * scp[e2] + shp[e2]);
                            vv = r;
                        }
                        *reinterpret_cast<bf16x8*>(&As[sr][sk + q * 8]) = vv;
                    }
                } else {
                    const float* p = (const float*)Ain + (size_t)grow * K + kc + sk;
#pragma unroll
                    for (int q = 0; q < 8; ++q) {
                        float4 v = *reinterpret_cast<const float4*>(p + q * 4);
                        if (scale) {
                            int c = kc + sk + q * 4;
                            float4 sc = *reinterpret_cast<const float4*>(scale + c);
                            float4 sh = *reinterpret_cast<const float4*>(shift + c);
                            v.x = v.x * sc.x + sh.x; v.y = v.y * sc.y + sh.y;
                            v.z = v.z * sc.z + sh.z; v.w = v.w * sc.w + sh.w;
                        }
                        bf16x4 cv = {(__bf16)v.x, (__bf16)v.y, (__bf16)v.z, (__bf16)v.w};
                        *reinterpret_cast<bf16x4*>(&As[sr][sk + q * 4]) = cv;
                    }
                }
            } else {
#pragma unroll
                for (int q = 0; q < 4; ++q)
                    *reinterpret_cast<bf16x8*>(&As[sr][sk + q * 8]) = (bf16x8)(__bf16)0.f;
            }
        }
        // ---- stage B ----
        {
            const __bf16* p = Bt + (size_t)(col0 + sr) * K + kc + sk;
#pragma unroll
            for (int q = 0; q < 4; ++q)
                *reinterpret_cast<bf16x8*>(&Bs[sr][sk + q * 8]) =
                    *reinterpret_cast<const bf16x8*>(p + q * 8);
        }
        __syncthreads();
#pragma unroll
        for (int ks = 0; ks < 64; ks += 32) {
            bf16x8 a0 = *reinterpret_cast<const bf16x8*>(&As[w * 32 + m][ks + quad * 8]);
            bf16x8 a1 = *reinterpret_cast<const bf16x8*>(&As[w * 32 + 16 + m][ks + quad * 8]);
#pragma unroll
            for (int nt = 0; nt < 8; ++nt) {
                bf16x8 b = *reinterpret_cast<const bf16x8*>(&Bs[nt * 16 + m][ks + quad * 8]);
                acc[0][nt] = __builtin_amdgcn_mfma_f32_16x16x32_bf16(a0, b, acc[0][nt], 0, 0, 0);
                acc[1][nt] = __builtin_amdgcn_mfma_f32_16x16x32_bf16(a1, b, acc[1][nt], 0, 0, 0);
            }
        }
        __syncthreads();
    }
    // ---- write C (bf16) ----
#pragma unroll
    for (int mt = 0; mt < 2; ++mt)
#pragma unroll
        for (int nt = 0; nt < 8; ++nt)
#pragma unroll
            for (int r = 0; r < 4; ++r) {
                int row = row0 + w * 32 + mt * 16 + quad * 4 + r;
                if (row < n) Cb[(size_t)row * M + col0 + nt * 16 + m] = (__bf16)acc[mt][nt][r];
            }
    // ---- fused attention dots: asrc/adst += sum_c xh[row][c]*att[c] (per head) ----
    {
        float asv[8], adv[8];
#pragma unroll
        for (int nt = 0; nt < 8; ++nt) {
            int c = col0 + nt * 16 + m;
            asv[nt] = att_s[c];
            adv[nt] = att_d[c];
        }
#pragma unroll
        for (int mt = 0; mt < 2; ++mt)
#pragma unroll
            for (int r = 0; r < 4; ++r) {
                int row = row0 + w * 32 + mt * 16 + quad * 4 + r;
                if (LC == 7) {  // single head per 128-col block
                    float pa = 0.f, pb = 0.f;
#pragma unroll
                    for (int nt = 0; nt < 8; ++nt) {
                        float v = acc[mt][nt][r];
                        pa += v * asv[nt];
                        pb += v * adv[nt];
                    }
#pragma unroll
                    for (int off = 1; off <= 8; off <<= 1) {
                        pa += __shfl_xor(pa, off);
                        pb += __shfl_xor(pb, off);
                    }
                    if (m == 0 && row < n) {
                        int h = (col0 >> 7) & 1;
                        atomicAdd(asrc + 2 * row + h, pa);
                        atomicAdd(adst + 2 * row + h, pb);
                    }
                } else {  // two heads inside the block (nt<4 -> h0, nt>=4 -> h1)
                    float p00 = 0.f, p01 = 0.f, p10 = 0.f, p11 = 0.f;
#pragma unroll
                    for (int nt = 0; nt < 8; ++nt) {
                        float v = acc[mt][nt][r];
                        if (nt < 4) { p00 += v * asv[nt]; p10 += v * adv[nt]; }
                        else        { p01 += v * asv[nt]; p11 += v * adv[nt]; }
                    }
#pragma unroll
                    for (int off = 1; off <= 8; off <<= 1) {
                        p00 += __shfl_xor(p00, off);
                        p01 += __shfl_xor(p01, off);
                        p10 += __shfl_xor(p10, off);
                        p11 += __shfl_xor(p11, off);
                    }
                    if (m == 0 && row < n) {
                        atomicAdd(asrc + 2 * row + 0, p00);
                        atomicAdd(asrc + 2 * row + 1, p01);
                        atomicAdd(adst + 2 * row + 0, p10);
                        atomicAdd(adst + 2 * row + 1, p11);
                    }
                }
            }
    }
}

// ---- final linear via MFMA: out[n,64](f32) = A[n,128](f32) @ lw[128,64] + lb
//      A exact via hi/lo bf16 split, lw rounded once to bf16.
__global__ __launch_bounds__(256) void k_lin(const float* __restrict__ A,
                                             const float* __restrict__ lw,
                                             const float* __restrict__ lb,
                                             float* __restrict__ out, int n) {
    __shared__ __align__(16) __bf16 Ahi[64][136];
    __shared__ __align__(16) __bf16 Alo[64][136];
    __shared__ __align__(16) __bf16 Bhi[64][136];
    const int row0 = blockIdx.x * 64;
    const int lane = threadIdx.x & 63, w = threadIdx.x >> 6;
    const int m = lane & 15, quad = lane >> 4;
    floatx4 acc[4];
#pragma unroll
    for (int i = 0; i < 4; ++i) acc[i] = (floatx4)0.f;

    {
        int sr = threadIdx.x >> 2, sk0 = (threadIdx.x & 3) * 32;
        int grow = row0 + sr;
#pragma unroll
        for (int q = 0; q < 8; ++q) {
            float4 v = make_float4(0.f, 0.f, 0.f, 0.f);
            if (grow < n) v = *reinterpret_cast<const float4*>(A + (size_t)grow * 128 + sk0 + q * 4);
            float vv[4] = {v.x, v.y, v.z, v.w};
#pragma unroll
            for (int i = 0; i < 4; ++i) {
                __bf16 h = (__bf16)vv[i];
                Ahi[sr][sk0 + q * 4 + i] = h;
                Alo[sr][sk0 + q * 4 + i] = (__bf16)(vv[i] - (float)h);
            }
        }
    }
    {
        int k0 = threadIdx.x >> 1, m0 = (threadIdx.x & 1) * 32;
#pragma unroll
        for (int q = 0; q < 8; ++q) {
            float4 v = *reinterpret_cast<const float4*>(lw + (size_t)k0 * 64 + m0 + q * 4);
            float vv[4] = {v.x, v.y, v.z, v.w};
#pragma unroll
            for (int i = 0; i < 4; ++i) Bhi[m0 + q * 4 + i][k0] = (__bf16)vv[i];
        }
    }
    __syncthreads();
#pragma unroll
    for (int ks = 0; ks < 128; ks += 32) {
        bf16x8 ah = *reinterpret_cast<const bf16x8*>(&Ahi[w * 16 + m][ks + quad * 8]);
        bf16x8 al = *reinterpret_cast<const bf16x8*>(&Alo[w * 16 + m][ks + quad * 8]);
#pragma unroll
        for (int nt = 0; nt < 4; ++nt) {
            bf16x8 bh = *reinterpret_cast<const bf16x8*>(&Bhi[nt * 16 + m][ks + quad * 8]);
            acc[nt] = __builtin_amdgcn_mfma_f32_16x16x32_bf16(ah, bh, acc[nt], 0, 0, 0);
            acc[nt] = __builtin_amdgcn_mfma_f32_16x16x32_bf16(al, bh, acc[nt], 0, 0, 0);
        }
    }
#pragma unroll
    for (int nt = 0; nt < 4; ++nt)
#pragma unroll
        for (int r = 0; r < 4; ++r) {
            int row = row0 + w * 16 + quad * 4 + r;
            int c = nt * 16 + m;
            if (row < n) out[(size_t)row * 64 + c] = acc[nt][r] + lb[c];
        }
}

// ---- GAT aggregation: no-max softmax, LDS slot stash, full-wave gather ----
//      One wave per node. Batch phase: 64 edges wide, exp weights -> LDS.
//      Gather phase: per edge 1 ds_read(broadcast) + 1 row gather + VEC fma.
template <int C, bool OUTBF16>
__global__ __launch_bounds__(256) void k_agg(const __bf16* __restrict__ xh,
                                             const float* __restrict__ asrc,
                                             const float* __restrict__ adst,
                                             const int* __restrict__ rowptr,
                                             const int* __restrict__ col,
                                             const float* __restrict__ bias,
                                             void* __restrict__ outv, int n) {
    constexpr int F = 2 * C;
    constexpr int VEC = F / 64;  // 4 (C=128) or 2 (C=64)
    __shared__ float4 slots[4][64];
    const int widx = threadIdx.x >> 6;
    const int node = blockIdx.x * 4 + widx;
    const int lane = threadIdx.x & 63;
    if (node >= n) return;
    const bool h1 = (lane * VEC) >= C;
    const int beg = rowptr[node];
    const int deg = rowptr[node + 1] - beg;
    const float2 adv = *reinterpret_cast<const float2*>(adst + 2 * node);
    const float2 asv = *reinterpret_cast<const float2*>(asrc + 2 * node);
    const float es0 = leaky(asv.x + adv.x), es1 = leaky(asv.y + adv.y);
    float acc[VEC] = {};
    float d0 = 0.f, d1 = 0.f;

    for (int base = 0; base < deg; base += 64) {
        const int cnt = min(64, deg - base);
        if (lane < cnt) {
            int s = col[beg + base + lane];
            float2 av = *reinterpret_cast<const float2*>(asrc + 2 * s);
            float w0 = __expf(leaky(av.x + adv.x));
            float w1 = __expf(leaky(av.y + adv.y));
            d0 += w0; d1 += w1;
            slots[widx][lane] = make_float4(__int_as_float(s), w0, w1, 0.f);
        }
        int j = 0;
        for (; j + 4 <= cnt; j += 4) {
            float4 s0 = slots[widx][j + 0];
            float4 s1 = slots[widx][j + 1];
            float4 s2 = slots[widx][j + 2];
            float4 s3 = slots[widx][j + 3];
            const __bf16* p0 = xh + (size_t)__float_as_int(s0.x) * F + lane * VEC;
            const __bf16* p1 = xh + (size_t)__float_as_int(s1.x) * F + lane * VEC;
            const __bf16* p2 = xh + (size_t)__float_as_int(s2.x) * F + lane * VEC;
            const __bf16* p3 = xh + (size_t)__float_as_int(s3.x) * F + lane * VEC;
            if constexpr (VEC == 4) {
                bf16x4 v0 = *reinterpret_cast<const bf16x4*>(p0);
                bf16x4 v1 = *reinterpret_cast<const bf16x4*>(p1);
                bf16x4 v2 = *reinterpret_cast<const bf16x4*>(p2);
                bf16x4 v3 = *reinterpret_cast<const bf16x4*>(p3);
                float w0 = h1 ? s0.z : s0.y, w1 = h1 ? s1.z : s1.y;
                float w2 = h1 ? s2.z : s2.y, w3 = h1 ? s3.z : s3.y;
#pragma unroll
                for (int q = 0; q < 4; ++q)
                    acc[q] += w0 * (float)v0[q] + w1 * (float)v1[q] +
                              w2 * (float)v2[q] + w3 * (float)v3[q];
            } else {
                bf16x2 v0 = *reinterpret_cast<const bf16x2*>(p0);
                bf16x2 v1 = *reinterpret_cast<const bf16x2*>(p1);
                bf16x2 v2 = *reinterpret_cast<const bf16x2*>(p2);
                bf16x2 v3 = *reinterpret_cast<const bf16x2*>(p3);
                float w0 = h1 ? s0.z : s0.y, w1 = h1 ? s1.z : s1.y;
                float w2 = h1 ? s2.z : s2.y, w3 = h1 ? s3.z : s3.y;
#pragma unroll
                for (int q = 0; q < 2; ++q)
                    acc[q] += w0 * (float)v0[q] + w1 * (float)v1[q] +
                              w2 * (float)v2[q] + w3 * (float)v3[q];
            }
        }
        for (; j < cnt; ++j) {
            float4 s0 = slots[widx][j];
            const __bf16* p0 = xh + (size_t)__float_as_int(s0.x) * F + lane * VEC;
            float w0 = h1 ? s0.z : s0.y;
            if constexpr (VEC == 4) {
                bf16x4 v0 = *reinterpret_cast<const bf16x4*>(p0);
#pragma unroll
                for (int q = 0; q < 4; ++q) acc[q] += w0 * (float)v0[q];
            } else {
                bf16x2 v0 = *reinterpret_cast<const bf16x2*>(p0);
#pragma unroll
                for (int q = 0; q < 2; ++q) acc[q] += w0 * (float)v0[q];
            }
        }
    }
    // denominators: reduce across all 64 lanes
#pragma unroll
    for (int off = 1; off <= 32; off <<= 1) {
        d0 += __shfl_xor(d0, off);
        d1 += __shfl_xor(d1, off);
    }
    // self loop
    float exs0 = __expf(es0), exs1 = __expf(es1);
    d0 += exs0; d1 += exs1;
    {
        float ws = h1 ? exs1 : exs0;
        const __bf16* p = xh + (size_t)node * F + lane * VEC;
        if constexpr (VEC == 4) {
            bf16x4 v = *reinterpret_cast<const bf16x4*>(p);
#pragma unroll
            for (int q = 0; q < 4; ++q) acc[q] += ws * (float)v[q];
        } else {
            bf16x2 v = *reinterpret_cast<const bf16x2*>(p);
#pragma unroll
            for (int q = 0; q < 2; ++q) acc[q] += ws * (float)v[q];
        }
    }
    float inv = 1.0f / ((h1 ? d1 : d0) + EPS_SM);
    float o[VEC];
#pragma unroll
    for (int q = 0; q < VEC; ++q) o[q] = fmaxf(acc[q] * inv + bias[lane * VEC + q], 0.f);
    if constexpr (OUTBF16) {
        __bf16* po = (__bf16*)outv + (size_t)node * F + lane * VEC;
        if constexpr (VEC == 4) {
            bf16x4 st = {(__bf16)o[0], (__bf16)o[1], (__bf16)o[2], (__bf16)o[3]};
            *reinterpret_cast<bf16x4*>(po) = st;
        } else {
            bf16x2 st = {(__bf16)o[0], (__bf16)o[1]};
            *reinterpret_cast<bf16x2*>(po) = st;
        }
    } else {
        float* po = (float*)outv + (size_t)node * F + lane * VEC;
        if constexpr (VEC == 4) *reinterpret_cast<float4*>(po) = make_float4(o[0], o[1], o[2], o[3]);
        else                    *reinterpret_cast<float2*>(po) = make_float2(o[0], o[1]);
    }
}

// ---------------- BatchNorm stats ----------------
template <typename T>
__global__ void k_bn_stats(const T* __restrict__ x, float* __restrict__ sums,
                           float* __restrict__ sqs, int n, int f) {
    int c = threadIdx.x;  // blockDim.x == f
    float s = 0.f, q = 0.f;
    for (int r = blockIdx.x; r < n; r += gridDim.x) {
        float v = (float)x[(size_t)r * f + c];
        s += v; q += v * v;
    }
    atomicAdd(&sums[c], s);
    atomicAdd(&sqs[c], q);
}

// ---------------- launch ----------------
extern "C" void kernel_launch(void* const* d_in, const int* in_sizes, int n_in,
                              void* d_out, int out_size, void* d_ws, size_t ws_size,
                              hipStream_t stream) {
    const float* x   = (const float*)d_in[0];
    const int*   ei  = (const int*)d_in[1];
    const float* W1  = (const float*)d_in[2];
    const float* as1 = (const float*)d_in[3];
    const float* ad1 = (const float*)d_in[4];
    const float* b1  = (const float*)d_in[5];
    const float* g1  = (const float*)d_in[6];
    const float* be1 = (const float*)d_in[7];
    const float* W2  = (const float*)d_in[8];
    const float* as2 = (const float*)d_in[9];
    const float* ad2 = (const float*)d_in[10];
    const float* b2  = (const float*)d_in[11];
    const float* g2  = (const float*)d_in[12];
    const float* be2 = (const float*)d_in[13];
    const float* W3  = (const float*)d_in[14];
    const float* as3 = (const float*)d_in[15];
    const float* ad3 = (const float*)d_in[16];
    const float* b3  = (const float*)d_in[17];
    const float* lw  = (const float*)d_in[18];
    const float* lb  = (const float*)d_in[19];
    float* outp = (float*)d_out;

    const int n = in_sizes[0] / 128;  // 50000
    const int e = in_sizes[1] / 2;    // 800000

    char* w = (char*)d_ws;
    size_t off = 0;
    auto alloc = [&](size_t bytes) -> void* {
        void* p = w + off;
        off += (bytes + 255) & ~(size_t)255;
        return p;
    };
    __bf16* xhb = (__bf16*)alloc((size_t)n * 256 * 2);  // GEMM outputs (per layer)
    __bf16* h1b = (__bf16*)alloc((size_t)n * 256 * 2);  // L1 agg out (bf16)
    __bf16* h2b = (__bf16*)alloc((size_t)n * 128 * 2);  // L2 agg out (bf16)
    float*  h3f = (float*)alloc((size_t)n * 128 * 4);   // L3 agg out (fp32, feeds k_lin)
    int* excl   = (int*)alloc((size_t)n * 4);
    int* rowptr = (int*)alloc((size_t)(n + 1) * 4);
    int* colb   = (int*)alloc((size_t)e * 4);
    int* bsum   = (int*)alloc(64 * 4);
    float* sc1  = (float*)alloc(256 * 4);
    float* sh1  = (float*)alloc(256 * 4);
    float* sc2  = (float*)alloc(128 * 4);
    float* sh2  = (float*)alloc(128 * 4);
    __bf16* Wb1 = (__bf16*)alloc(256 * 128 * 2);
    __bf16* Wb2 = (__bf16*)alloc(128 * 256 * 2);
    __bf16* Wb3 = (__bf16*)alloc(128 * 128 * 2);
    // ---- contiguous zero block ----
    char* zb_begin = (char*)(w + off);
    int* deg    = (int*)alloc((size_t)n * 4);
    int* fill   = (int*)alloc((size_t)n * 4);
    float* bn1  = (float*)alloc(512 * 4);
    float* bn2  = (float*)alloc(512 * 4);
    int* dcnt   = (int*)alloc(256);
    float* as1p = (float*)alloc((size_t)n * 2 * 4);
    float* ad1p = (float*)alloc((size_t)n * 2 * 4);
    float* as2p = (float*)alloc((size_t)n * 2 * 4);
    float* ad2p = (float*)alloc((size_t)n * 2 * 4);
    float* as3p = (float*)alloc((size_t)n * 2 * 4);
    float* ad3p = (float*)alloc((size_t)n * 2 * 4);
    char* zb_end = (char*)(w + off);

    const int nb1 = (n + 1023) / 1024;

    hipMemsetAsync(zb_begin, 0, (size_t)(zb_end - zb_begin), stream);

    // edge dtype detect + CSR
    k_detect<<<4, 256, 0, stream>>>(ei, dcnt, e);
    k_hist<<<(e + 255) / 256, 256, 0, stream>>>(ei, dcnt, deg, e);
    k_scan1<<<nb1, 1024, 0, stream>>>(deg, excl, bsum, n);
    k_scan2<<<1, 1, 0, stream>>>(bsum, nb1);
    k_scan3<<<(n + 255) / 256, 256, 0, stream>>>(excl, bsum, rowptr, n, e);
    k_scatter<<<(e + 255) / 256, 256, 0, stream>>>(ei, dcnt, rowptr, fill, colb, e);

    // weight convert
    k_wconv<<<(256 * 128 + 255) / 256, 256, 0, stream>>>(W1, Wb1, 7, 256, 256 * 128);
    k_wconv<<<(128 * 256 + 255) / 256, 256, 0, stream>>>(W2, Wb2, 8, 128, 128 * 256);
    k_wconv<<<(128 * 128 + 255) / 256, 256, 0, stream>>>(W3, Wb3, 7, 128, 128 * 128);

    const int nwb = (n + 3) / 4;       // agg blocks (4 waves/block)
    const int nrow = (n + 127) / 128;  // gemm row blocks

    // ---- layer 1: 128 -> 2x128 ----
    k_gemm<128, 7, false><<<dim3(2, nrow), 256, 0, stream>>>(
        x, Wb1, xhb, n, 256, nullptr, nullptr, as1, ad1, as1p, ad1p);
    k_agg<128, true><<<nwb, 256, 0, stream>>>(xhb, as1p, ad1p, rowptr, colb, b1, h1b, n);
    k_bn_stats<__bf16><<<256, 256, 0, stream>>>(h1b, bn1, bn1 + 256, n, 256);
    k_bn_prep<<<1, 256, 0, stream>>>(bn1, bn1 + 256, g1, be1, sc1, sh1, n, 256);

    // ---- layer 2: 256 -> 2x64 (BN1 fused into A-staging) ----
    k_gemm<256, 6, true><<<dim3(1, nrow), 256, 0, stream>>>(
        h1b, Wb2, xhb, n, 128, sc1, sh1, as2, ad2, as2p, ad2p);
    k_agg<64, true><<<nwb, 256, 0, stream>>>(xhb, as2p, ad2p, rowptr, colb, b2, h2b, n);
    k_bn_stats<__bf16><<<256, 128, 0, stream>>>(h2b, bn2, bn2 + 256, n, 128);
    k_bn_prep<<<1, 256, 0, stream>>>(bn2, bn2 + 256, g2, be2, sc2, sh2, n, 128);

    // ---- layer 3: 128 -> 2x64 (BN2 fused) ----
    k_gemm<128, 6, true><<<dim3(1, nrow), 256, 0, stream>>>(
        h2b, Wb3, xhb, n, 128, sc2, sh2, as3, ad3, as3p, ad3p);
    k_agg<64, false><<<nwb, 256, 0, stream>>>(xhb, as3p, ad3p, rowptr, colb, b3, h3f, n);

    // ---- final linear: [n,128] @ [128,64] + lb ----
    k_lin<<<(n + 63) / 64, 256, 0, stream>>>(h3f, lw, lb, outp, n);
}

// Round 7
// 477.049 us; speedup vs baseline: 1.6921x; 1.1184x over previous
//
#include <hip/hip_runtime.h>
#include <hip/hip_bf16.h>

#define NEG_SLOPE 0.2f
#define EPS_BN 1e-5f
#define EPS_SM 1e-16f

typedef __bf16 bf16x8 __attribute__((ext_vector_type(8)));
typedef __bf16 bf16x4 __attribute__((ext_vector_type(4)));
typedef float floatx4 __attribute__((ext_vector_type(4)));

__device__ __forceinline__ float leaky(float x) { return x > 0.f ? x : NEG_SLOPE * x; }

// ---------------- edge dtype detection (int32 vs int64 layout) ----------------
__global__ void k_detect(const int* __restrict__ ei, int* __restrict__ cnt, int e) {
    int i = threadIdx.x + blockIdx.x * blockDim.x;
    if (i < 1024 && 2 * i + 1 < 2 * e) {
        if (ei[2 * i + 1] != 0) atomicAdd(cnt, 1);
    }
}

// ---------------- CSR build ----------------
// hist also records per-edge rank so scatter needs no atomics.
__global__ void k_hist(const int* __restrict__ ei, const int* __restrict__ cnt,
                       int* __restrict__ deg, int* __restrict__ rnk, int e) {
    int g = threadIdx.x + blockIdx.x * blockDim.x;
    if (g >= e) return;
    bool is64 = (*cnt) < 512;
    int d = is64 ? ei[2 * (e + g)] : ei[e + g];
    rnk[g] = atomicAdd(&deg[d], 1);
}

__global__ __launch_bounds__(1024) void k_scan1(const int* __restrict__ deg,
                                                int* __restrict__ excl,
                                                int* __restrict__ bsum, int n) {
    __shared__ int sm[1024];
    int tid = threadIdx.x;
    int g = blockIdx.x * 1024 + tid;
    int v = (g < n) ? deg[g] : 0;
    sm[tid] = v;
    __syncthreads();
    for (int off = 1; off < 1024; off <<= 1) {
        int t = (tid >= off) ? sm[tid - off] : 0;
        __syncthreads();
        sm[tid] += t;
        __syncthreads();
    }
    if (g < n) excl[g] = sm[tid] - v;
    if (tid == 1023) bsum[blockIdx.x] = sm[1023];
}

// scan3 with inline bsum prefix (merged scan2): each 256-id block spans one 1024-chunk.
__global__ void k_scan3(const int* __restrict__ excl, const int* __restrict__ bsum,
                        int* __restrict__ rowptr, int n, int e) {
    __shared__ int pref;
    int g = threadIdx.x + blockIdx.x * blockDim.x;
    if (threadIdx.x == 0) {
        int chunk = (blockIdx.x * blockDim.x) >> 10;
        int acc = 0;
        for (int i = 0; i < chunk; ++i) acc += bsum[i];
        pref = acc;
    }
    __syncthreads();
    if (g < n) rowptr[g] = excl[g] + pref;
    if (g == 0) rowptr[n] = e;
}

__global__ void k_scatter(const int* __restrict__ ei, const int* __restrict__ cnt,
                          const int* __restrict__ rowptr, const int* __restrict__ rnk,
                          int* __restrict__ col, int e) {
    int g = threadIdx.x + blockIdx.x * blockDim.x;
    if (g >= e) return;
    bool is64 = (*cnt) < 512;
    int s = is64 ? ei[2 * g] : ei[g];
    int d = is64 ? ei[2 * (e + g)] : ei[e + g];
    col[rowptr[d] + rnk[g]] = s;
}

// -------- merged weight convert+transpose: Wb[m][k] = bf16(W[k][m]) for all 3 ------
__global__ void k_wconv(const float* __restrict__ W1, __bf16* __restrict__ Wb1,
                        const float* __restrict__ W2, __bf16* __restrict__ Wb2,
                        const float* __restrict__ W3, __bf16* __restrict__ Wb3) {
    int idx = threadIdx.x + blockIdx.x * blockDim.x;
    if (idx < 32768) {  // W1: K=128 (shift 7), M=256
        int mm = idx >> 7, kk = idx & 127;
        Wb1[idx] = (__bf16)W1[(size_t)kk * 256 + mm];
    } else if (idx < 65536) {  // W2: K=256 (shift 8), M=128
        int i2 = idx - 32768;
        int mm = i2 >> 8, kk = i2 & 255;
        Wb2[i2] = (__bf16)W2[(size_t)kk * 128 + mm];
    } else if (idx < 81920) {  // W3: K=128, M=128
        int i3 = idx - 65536;
        int mm = i3 >> 7, kk = i3 & 127;
        Wb3[i3] = (__bf16)W3[(size_t)kk * 128 + mm];
    }
}

// ---- bf16 MFMA GEMM, 128x128 tile, inline BN prep + fused attn dots epilogue.
template <int K, int LC, bool BF16IN>
__global__ __launch_bounds__(256) void k_gemm(const void* __restrict__ Ain,
                                              const __bf16* __restrict__ Bt,
                                              __bf16* __restrict__ Cb, int n, int M,
                                              const float* __restrict__ bnsums,
                                              const float* __restrict__ gam,
                                              const float* __restrict__ bet,
                                              const float* __restrict__ att_s,
                                              const float* __restrict__ att_d,
                                              float* __restrict__ asrc,
                                              float* __restrict__ adst) {
    __shared__ __align__(16) __bf16 As[128][72];
    __shared__ __align__(16) __bf16 Bs[128][72];
    __shared__ float sc_lds[K], sh_lds[K];
    const int row0 = blockIdx.y * 128, col0 = blockIdx.x * 128;
    const int lane = threadIdx.x & 63, w = threadIdx.x >> 6;
    const int m = lane & 15, quad = lane >> 4;

    if (bnsums) {
        for (int c = threadIdx.x; c < K; c += 256) {
            float mean = bnsums[c] / n;
            float var = bnsums[256 + c] / n - mean * mean;
            float sc = gam[c] * rsqrtf(var + EPS_BN);
            sc_lds[c] = sc;
            sh_lds[c] = bet[c] - mean * sc;
        }
        __syncthreads();
    }

    floatx4 acc[2][8];
#pragma unroll
    for (int i = 0; i < 2; ++i)
#pragma unroll
        for (int j = 0; j < 8; ++j) acc[i][j] = (floatx4)0.f;

    const int sr = threadIdx.x >> 1;        // 0..127
    const int sk = (threadIdx.x & 1) * 32;  // 0,32

    for (int kc = 0; kc < K; kc += 64) {
        {
            int grow = row0 + sr;
            if (grow < n) {
                if (BF16IN) {
                    const __bf16* p = (const __bf16*)Ain + (size_t)grow * K + kc + sk;
#pragma unroll
                    for (int q = 0; q < 4; ++q) {
                        bf16x8 vv = *reinterpret_cast<const bf16x8*>(p + q * 8);
                        if (bnsums) {
                            int c = kc + sk + q * 8;
                            bf16x8 r;
#pragma unroll
                            for (int e2 = 0; e2 < 8; ++e2)
                                r[e2] = (__bf16)((float)vv[e2] * sc_lds[c + e2] + sh_lds[c + e2]);
                            vv = r;
                        }
                        *reinterpret_cast<bf16x8*>(&As[sr][sk + q * 8]) = vv;
                    }
                } else {
                    const float* p = (const float*)Ain + (size_t)grow * K + kc + sk;
#pragma unroll
                    for (int q = 0; q < 8; ++q) {
                        float4 v = *reinterpret_cast<const float4*>(p + q * 4);
                        bf16x4 cv = {(__bf16)v.x, (__bf16)v.y, (__bf16)v.z, (__bf16)v.w};
                        *reinterpret_cast<bf16x4*>(&As[sr][sk + q * 4]) = cv;
                    }
                }
            } else {
#pragma unroll
                for (int q = 0; q < 4; ++q)
                    *reinterpret_cast<bf16x8*>(&As[sr][sk + q * 8]) = (bf16x8)(__bf16)0.f;
            }
        }
        {
            const __bf16* p = Bt + (size_t)(col0 + sr) * K + kc + sk;
#pragma unroll
            for (int q = 0; q < 4; ++q)
                *reinterpret_cast<bf16x8*>(&Bs[sr][sk + q * 8]) =
                    *reinterpret_cast<const bf16x8*>(p + q * 8);
        }
        __syncthreads();
#pragma unroll
        for (int ks = 0; ks < 64; ks += 32) {
            bf16x8 a0 = *reinterpret_cast<const bf16x8*>(&As[w * 32 + m][ks + quad * 8]);
            bf16x8 a1 = *reinterpret_cast<const bf16x8*>(&As[w * 32 + 16 + m][ks + quad * 8]);
#pragma unroll
            for (int nt = 0; nt < 8; ++nt) {
                bf16x8 b = *reinterpret_cast<const bf16x8*>(&Bs[nt * 16 + m][ks + quad * 8]);
                acc[0][nt] = __builtin_amdgcn_mfma_f32_16x16x32_bf16(a0, b, acc[0][nt], 0, 0, 0);
                acc[1][nt] = __builtin_amdgcn_mfma_f32_16x16x32_bf16(a1, b, acc[1][nt], 0, 0, 0);
            }
        }
        __syncthreads();
    }
#pragma unroll
    for (int mt = 0; mt < 2; ++mt)
#pragma unroll
        for (int nt = 0; nt < 8; ++nt)
#pragma unroll
            for (int r = 0; r < 4; ++r) {
                int row = row0 + w * 32 + mt * 16 + quad * 4 + r;
                if (row < n) Cb[(size_t)row * M + col0 + nt * 16 + m] = (__bf16)acc[mt][nt][r];
            }
    // fused attention dots
    {
        float asv[8], adv[8];
#pragma unroll
        for (int nt = 0; nt < 8; ++nt) {
            int c = col0 + nt * 16 + m;
            asv[nt] = att_s[c];
            adv[nt] = att_d[c];
        }
#pragma unroll
        for (int mt = 0; mt < 2; ++mt)
#pragma unroll
            for (int r = 0; r < 4; ++r) {
                int row = row0 + w * 32 + mt * 16 + quad * 4 + r;
                if (LC == 7) {
                    float pa = 0.f, pb = 0.f;
#pragma unroll
                    for (int nt = 0; nt < 8; ++nt) {
                        float v = acc[mt][nt][r];
                        pa += v * asv[nt];
                        pb += v * adv[nt];
                    }
#pragma unroll
                    for (int off = 1; off <= 8; off <<= 1) {
                        pa += __shfl_xor(pa, off);
                        pb += __shfl_xor(pb, off);
                    }
                    if (m == 0 && row < n) {
                        int h = (col0 >> 7) & 1;
                        atomicAdd(asrc + 2 * row + h, pa);
                        atomicAdd(adst + 2 * row + h, pb);
                    }
                } else {
                    float p00 = 0.f, p01 = 0.f, p10 = 0.f, p11 = 0.f;
#pragma unroll
                    for (int nt = 0; nt < 8; ++nt) {
                        float v = acc[mt][nt][r];
                        if (nt < 4) { p00 += v * asv[nt]; p10 += v * adv[nt]; }
                        else        { p01 += v * asv[nt]; p11 += v * adv[nt]; }
                    }
#pragma unroll
                    for (int off = 1; off <= 8; off <<= 1) {
                        p00 += __shfl_xor(p00, off);
                        p01 += __shfl_xor(p01, off);
                        p10 += __shfl_xor(p10, off);
                        p11 += __shfl_xor(p11, off);
                    }
                    if (m == 0 && row < n) {
                        atomicAdd(asrc + 2 * row + 0, p00);
                        atomicAdd(asrc + 2 * row + 1, p01);
                        atomicAdd(adst + 2 * row + 0, p10);
                        atomicAdd(adst + 2 * row + 1, p11);
                    }
                }
            }
    }
}

// ---- final linear via MFMA: out[n,64](f32) = A[n,128](f32) @ lw[128,64] + lb ----
__global__ __launch_bounds__(256) void k_lin(const float* __restrict__ A,
                                             const float* __restrict__ lw,
                                             const float* __restrict__ lb,
                                             float* __restrict__ out, int n) {
    __shared__ __align__(16) __bf16 Ahi[64][136];
    __shared__ __align__(16) __bf16 Alo[64][136];
    __shared__ __align__(16) __bf16 Bhi[64][136];
    const int row0 = blockIdx.x * 64;
    const int lane = threadIdx.x & 63, w = threadIdx.x >> 6;
    const int m = lane & 15, quad = lane >> 4;
    floatx4 acc[4];
#pragma unroll
    for (int i = 0; i < 4; ++i) acc[i] = (floatx4)0.f;
    {
        int sr = threadIdx.x >> 2, sk0 = (threadIdx.x & 3) * 32;
        int grow = row0 + sr;
#pragma unroll
        for (int q = 0; q < 8; ++q) {
            float4 v = make_float4(0.f, 0.f, 0.f, 0.f);
            if (grow < n) v = *reinterpret_cast<const float4*>(A + (size_t)grow * 128 + sk0 + q * 4);
            float vv[4] = {v.x, v.y, v.z, v.w};
#pragma unroll
            for (int i = 0; i < 4; ++i) {
                __bf16 h = (__bf16)vv[i];
                Ahi[sr][sk0 + q * 4 + i] = h;
                Alo[sr][sk0 + q * 4 + i] = (__bf16)(vv[i] - (float)h);
            }
        }
    }
    {
        int k0 = threadIdx.x >> 1, m0 = (threadIdx.x & 1) * 32;
#pragma unroll
        for (int q = 0; q < 8; ++q) {
            float4 v = *reinterpret_cast<const float4*>(lw + (size_t)k0 * 64 + m0 + q * 4);
            float vv[4] = {v.x, v.y, v.z, v.w};
#pragma unroll
            for (int i = 0; i < 4; ++i) Bhi[m0 + q * 4 + i][k0] = (__bf16)vv[i];
        }
    }
    __syncthreads();
#pragma unroll
    for (int ks = 0; ks < 128; ks += 32) {
        bf16x8 ah = *reinterpret_cast<const bf16x8*>(&Ahi[w * 16 + m][ks + quad * 8]);
        bf16x8 al = *reinterpret_cast<const bf16x8*>(&Alo[w * 16 + m][ks + quad * 8]);
#pragma unroll
        for (int nt = 0; nt < 4; ++nt) {
            bf16x8 bh = *reinterpret_cast<const bf16x8*>(&Bhi[nt * 16 + m][ks + quad * 8]);
            acc[nt] = __builtin_amdgcn_mfma_f32_16x16x32_bf16(ah, bh, acc[nt], 0, 0, 0);
            acc[nt] = __builtin_amdgcn_mfma_f32_16x16x32_bf16(al, bh, acc[nt], 0, 0, 0);
        }
    }
#pragma unroll
    for (int nt = 0; nt < 4; ++nt)
#pragma unroll
        for (int r = 0; r < 4; ++r) {
            int row = row0 + w * 16 + quad * 4 + r;
            int c = nt * 16 + m;
            if (row < n) out[(size_t)row * 64 + c] = acc[nt][r] + lb[c];
        }
}

// ---- GAT aggregation: grouped gather, bf16x8 (16B) loads, LDS byte-offset slots ----
//      G = F/8 lanes per edge-group; NG = 64/G edges in flight per wave-step.
template <int C, bool OUTBF16>
__global__ __launch_bounds__(256) void k_agg(const __bf16* __restrict__ xh,
                                             const float* __restrict__ asrc,
                                             const float* __restrict__ adst,
                                             const int* __restrict__ rowptr,
                                             const int* __restrict__ col,
                                             const float* __restrict__ bias,
                                             void* __restrict__ outv, int n) {
    constexpr int F = 2 * C;          // bf16 per row (256 or 128)
    constexpr int G = F / 8;          // lanes per edge (32 or 16)
    constexpr int NG = 64 / G;        // edges per wave-step (2 or 4)
    constexpr int GSH = (G == 32) ? 5 : 4;
    __shared__ float4 slots[4][72];   // 64 + 8 zero-pad for unrolled overrun
    const int widx = threadIdx.x >> 6;
    const int node = blockIdx.x * 4 + widx;
    const int lane = threadIdx.x & 63;
    if (node >= n) return;
    const int t = lane & (G - 1);
    const int g = lane >> GSH;
    const bool h1 = (t * 8) >= C;
    if (lane < 8) slots[widx][64 + lane] = make_float4(0.f, 0.f, 0.f, 0.f);
    const int beg = rowptr[node];
    const int deg = rowptr[node + 1] - beg;
    const float2 adv = *reinterpret_cast<const float2*>(adst + 2 * node);
    const float2 asv = *reinterpret_cast<const float2*>(asrc + 2 * node);
    const float es0 = leaky(asv.x + adv.x), es1 = leaky(asv.y + adv.y);
    float acc[8] = {};
    float d0 = 0.f, d1 = 0.f;

    for (int base = 0; base < deg; base += 64) {
        const int cnt = min(64, deg - base);
        float4 sv = make_float4(0.f, 0.f, 0.f, 0.f);
        if (lane < cnt) {
            int s = col[beg + base + lane];
            float2 av = *reinterpret_cast<const float2*>(asrc + 2 * s);
            float w0 = __expf(leaky(av.x + adv.x));
            float w1 = __expf(leaky(av.y + adv.y));
            d0 += w0; d1 += w1;
            sv = make_float4(__int_as_float(s * (F * 2)), w0, w1, 0.f);
        }
        slots[widx][lane] = sv;  // wave-synchronous; zero weights beyond cnt
        for (int j = g; j < cnt; j += 2 * NG) {
            float4 s0 = slots[widx][j];
            float4 s1 = slots[widx][j + NG];  // may be zero-slot; offset 0 is safe
            const char* p0 = (const char*)xh + (unsigned)__float_as_int(s0.x);
            const char* p1 = (const char*)xh + (unsigned)__float_as_int(s1.x);
            bf16x8 v0 = *reinterpret_cast<const bf16x8*>(p0 + t * 16);
            bf16x8 v1 = *reinterpret_cast<const bf16x8*>(p1 + t * 16);
            float w0 = h1 ? s0.z : s0.y;
            float w1 = h1 ? s1.z : s1.y;
#pragma unroll
            for (int q = 0; q < 8; ++q) acc[q] += w0 * (float)v0[q] + w1 * (float)v1[q];
        }
    }
    // denominators across whole wave
#pragma unroll
    for (int off = 1; off <= 32; off <<= 1) {
        d0 += __shfl_xor(d0, off);
        d1 += __shfl_xor(d1, off);
    }
    // combine edge-groups (lanes with equal t across g hold same channels)
#pragma unroll
    for (int q = 0; q < 8; ++q) {
#pragma unroll
        for (int off = G; off < 64; off <<= 1) acc[q] += __shfl_xor(acc[q], off);
    }
    // self loop AFTER combine (each replica adds identical term)
    float exs0 = __expf(es0), exs1 = __expf(es1);
    d0 += exs0; d1 += exs1;
    {
        float ws = h1 ? exs1 : exs0;
        const __bf16* p = xh + (size_t)node * F + t * 8;
        bf16x8 v = *reinterpret_cast<const bf16x8*>(p);
#pragma unroll
        for (int q = 0; q < 8; ++q) acc[q] += ws * (float)v[q];
    }
    float inv = 1.0f / ((h1 ? d1 : d0) + EPS_SM);
    float o[8];
#pragma unroll
    for (int q = 0; q < 8; ++q) o[q] = fmaxf(acc[q] * inv + bias[t * 8 + q], 0.f);
    if (g == 0) {
        if constexpr (OUTBF16) {
            __bf16* po = (__bf16*)outv + (size_t)node * F + t * 8;
            bf16x8 st;
#pragma unroll
            for (int q = 0; q < 8; ++q) st[q] = (__bf16)o[q];
            *reinterpret_cast<bf16x8*>(po) = st;
        } else {
            float* po = (float*)outv + (size_t)node * F + t * 8;
            *reinterpret_cast<float4*>(po) = make_float4(o[0], o[1], o[2], o[3]);
            *reinterpret_cast<float4*>(po + 4) = make_float4(o[4], o[5], o[6], o[7]);
        }
    }
}

// ---------------- BatchNorm stats ----------------
template <typename T>
__global__ void k_bn_stats(const T* __restrict__ x, float* __restrict__ sums,
                           float* __restrict__ sqs, int n, int f) {
    int c = threadIdx.x;
    float s = 0.f, q = 0.f;
    for (int r = blockIdx.x; r < n; r += gridDim.x) {
        float v = (float)x[(size_t)r * f + c];
        s += v; q += v * v;
    }
    atomicAdd(&sums[c], s);
    atomicAdd(&sqs[c], q);
}

// ---------------- launch ----------------
extern "C" void kernel_launch(void* const* d_in, const int* in_sizes, int n_in,
                              void* d_out, int out_size, void* d_ws, size_t ws_size,
                              hipStream_t stream) {
    const float* x   = (const float*)d_in[0];
    const int*   ei  = (const int*)d_in[1];
    const float* W1  = (const float*)d_in[2];
    const float* as1 = (const float*)d_in[3];
    const float* ad1 = (const float*)d_in[4];
    const float* b1  = (const float*)d_in[5];
    const float* g1  = (const float*)d_in[6];
    const float* be1 = (const float*)d_in[7];
    const float* W2  = (const float*)d_in[8];
    const float* as2 = (const float*)d_in[9];
    const float* ad2 = (const float*)d_in[10];
    const float* b2  = (const float*)d_in[11];
    const float* g2  = (const float*)d_in[12];
    const float* be2 = (const float*)d_in[13];
    const float* W3  = (const float*)d_in[14];
    const float* as3 = (const float*)d_in[15];
    const float* ad3 = (const float*)d_in[16];
    const float* b3  = (const float*)d_in[17];
    const float* lw  = (const float*)d_in[18];
    const float* lb  = (const float*)d_in[19];
    float* outp = (float*)d_out;

    const int n = in_sizes[0] / 128;  // 50000
    const int e = in_sizes[1] / 2;    // 800000

    char* w = (char*)d_ws;
    size_t off = 0;
    auto alloc = [&](size_t bytes) -> void* {
        void* p = w + off;
        off += (bytes + 255) & ~(size_t)255;
        return p;
    };
    __bf16* xhb = (__bf16*)alloc((size_t)n * 256 * 2);
    __bf16* h1b = (__bf16*)alloc((size_t)n * 256 * 2);
    __bf16* h2b = (__bf16*)alloc((size_t)n * 128 * 2);
    float*  h3f = (float*)alloc((size_t)n * 128 * 4);
    int* excl   = (int*)alloc((size_t)n * 4);
    int* rowptr = (int*)alloc((size_t)(n + 1) * 4);
    int* colb   = (int*)alloc((size_t)e * 4);
    int* rnk    = (int*)alloc((size_t)e * 4);
    int* bsum   = (int*)alloc(64 * 4);
    __bf16* Wb1 = (__bf16*)alloc(256 * 128 * 2);
    __bf16* Wb2 = (__bf16*)alloc(128 * 256 * 2);
    __bf16* Wb3 = (__bf16*)alloc(128 * 128 * 2);
    // ---- contiguous zero block ----
    char* zb_begin = (char*)(w + off);
    int* deg    = (int*)alloc((size_t)n * 4);
    float* bn1  = (float*)alloc(512 * 4);
    float* bn2  = (float*)alloc(512 * 4);
    int* dcnt   = (int*)alloc(256);
    float* as1p = (float*)alloc((size_t)n * 2 * 4);
    float* ad1p = (float*)alloc((size_t)n * 2 * 4);
    float* as2p = (float*)alloc((size_t)n * 2 * 4);
    float* ad2p = (float*)alloc((size_t)n * 2 * 4);
    float* as3p = (float*)alloc((size_t)n * 2 * 4);
    float* ad3p = (float*)alloc((size_t)n * 2 * 4);
    char* zb_end = (char*)(w + off);

    const int nb1 = (n + 1023) / 1024;

    hipMemsetAsync(zb_begin, 0, (size_t)(zb_end - zb_begin), stream);

    k_detect<<<4, 256, 0, stream>>>(ei, dcnt, e);
    k_hist<<<(e + 255) / 256, 256, 0, stream>>>(ei, dcnt, deg, rnk, e);
    k_scan1<<<nb1, 1024, 0, stream>>>(deg, excl, bsum, n);
    k_scan3<<<(n + 255) / 256, 256, 0, stream>>>(excl, bsum, rowptr, n, e);
    k_scatter<<<(e + 255) / 256, 256, 0, stream>>>(ei, dcnt, rowptr, rnk, colb, e);
    k_wconv<<<(81920 + 255) / 256, 256, 0, stream>>>(W1, Wb1, W2, Wb2, W3, Wb3);

    const int nwb = (n + 3) / 4;
    const int nrow = (n + 127) / 128;

    // ---- layer 1: 128 -> 2x128 ----
    k_gemm<128, 7, false><<<dim3(2, nrow), 256, 0, stream>>>(
        x, Wb1, xhb, n, 256, nullptr, nullptr, nullptr, as1, ad1, as1p, ad1p);
    k_agg<128, true><<<nwb, 256, 0, stream>>>(xhb, as1p, ad1p, rowptr, colb, b1, h1b, n);
    k_bn_stats<__bf16><<<256, 256, 0, stream>>>(h1b, bn1, bn1 + 256, n, 256);

    // ---- layer 2: 256 -> 2x64 (BN1 inline in GEMM prologue) ----
    k_gemm<256, 6, true><<<dim3(1, nrow), 256, 0, stream>>>(
        h1b, Wb2, xhb, n, 128, bn1, g1, be1, as2, ad2, as2p, ad2p);
    k_agg<64, true><<<nwb, 256, 0, stream>>>(xhb, as2p, ad2p, rowptr, colb, b2, h2b, n);
    k_bn_stats<__bf16><<<256, 128, 0, stream>>>(h2b, bn2, bn2 + 256, n, 128);

    // ---- layer 3: 128 -> 2x64 (BN2 inline) ----
    k_gemm<128, 6, true><<<dim3(1, nrow), 256, 0, stream>>>(
        h2b, Wb3, xhb, n, 128, bn2, g2, be2, as3, ad3, as3p, ad3p);
    k_agg<64, false><<<nwb, 256, 0, stream>>>(xhb, as3p, ad3p, rowptr, colb, b3, h3f, n);

    // ---- final linear ----
    k_lin<<<(n + 63) / 64, 256, 0, stream>>>(h3f, lw, lb, outp, n);
}